// Round 8
// baseline (435.797 us; speedup 1.0000x reference)
//
#include <hip/hip_runtime.h>
#include <math.h>

// ---------------------------------------------------------------------------
// Shapes: 5 streams x B=2 x N=1024 x C=768; H=12 heads x D=64; AD=8; HID=3072
// TOK = 5*2*1024 = 10240 rows everywhere.
// ---------------------------------------------------------------------------
typedef __bf16 bf16;
typedef __attribute__((ext_vector_type(8))) __bf16 bf16x8;
typedef __attribute__((ext_vector_type(4))) __bf16 bf16x4;
typedef __attribute__((ext_vector_type(4))) float f32x4;
typedef __attribute__((ext_vector_type(16))) float f32x16;

#define TOK   10240
#define CD    768
#define NQKV  2304
#define NHID  3072
#define SEQ   1024
#define NH    12

__device__ __forceinline__ f32x4 mfma16(bf16x8 a, bf16x8 b, f32x4 c) {
  return __builtin_amdgcn_mfma_f32_16x16x32_bf16(a, b, c, 0, 0, 0);
}
__device__ __forceinline__ f32x16 mfma32(bf16x8 a, bf16x8 b, f32x16 c) {
  return __builtin_amdgcn_mfma_f32_32x32x16_bf16(a, b, c, 0, 0, 0);
}

// async global->LDS, 16B per lane. LDS dest must be wave-uniform base;
// HW writes at base + lane*16. Global src is per-lane.
__device__ __forceinline__ void gload16(const void* g, void* l) {
  __builtin_amdgcn_global_load_lds(
      (const __attribute__((address_space(1))) void*)g,
      (__attribute__((address_space(3))) void*)l, 16, 0, 0);
}

__device__ __forceinline__ unsigned pack2(bf16 a, bf16 b) {
  union { unsigned short u[2]; unsigned v; } x;
  x.u[0] = __builtin_bit_cast(unsigned short, a);
  x.u[1] = __builtin_bit_cast(unsigned short, b);
  return x.v;
}

__device__ __forceinline__ f32x4 b4tof(const bf16* p) {
  bf16x4 v = *(const bf16x4*)p;
  f32x4 r;
#pragma unroll
  for (int j = 0; j < 4; ++j) r[j] = (float)v[j];
  return r;
}

// tanh-approx GELU (abs err ~3e-3, fine vs 0.11 threshold); __expf is HW exp
__device__ __forceinline__ float fast_gelu(float v) {
  float u = 0.7978845608f * (v + 0.044715f * v * v * v);
  float e = __expf(fminf(2.f * u, 30.f));
  return 0.5f * v * (1.f + (e - 1.f) / (e + 1.f));
}

// ---------------------------------------------------------------------------
// Weight convert+transpose: in [K][N] f32 -> out [N][K] bf16
// ---------------------------------------------------------------------------
__global__ __launch_bounds__(256) void transpose_to_bf16(
    const float* __restrict__ in, bf16* __restrict__ out, int K, int N) {
  __shared__ float tile[32][33];
  const int bn = blockIdx.x * 32, bk = blockIdx.y * 32;
  const int r = threadIdx.x >> 5, c = threadIdx.x & 31;
#pragma unroll
  for (int i = 0; i < 4; ++i)
    tile[r + 8 * i][c] = in[(size_t)(bk + r + 8 * i) * N + bn + c];
  __syncthreads();
#pragma unroll
  for (int i = 0; i < 4; ++i)
    out[(size_t)(bn + r + 8 * i) * K + bk + c] = (bf16)tile[c][r + 8 * i];
}

// ---------------------------------------------------------------------------
// LN over 5 stacked stream inputs -> bf16 [TOK][768]
// ---------------------------------------------------------------------------
__global__ __launch_bounds__(256) void ln5_kernel(
    const float* __restrict__ x0, const float* __restrict__ x1,
    const float* __restrict__ x2, const float* __restrict__ x3,
    const float* __restrict__ x4, const float* __restrict__ g,
    const float* __restrict__ b, bf16* __restrict__ out) {
  const int w = threadIdx.x >> 6, lane = threadIdx.x & 63;
  const int row = blockIdx.x * 4 + w;
  const int s = row >> 11, rem = row & 2047;
  const float* xp;
  switch (s) {
    case 0: xp = x0; break; case 1: xp = x1; break; case 2: xp = x2; break;
    case 3: xp = x3; break; default: xp = x4; break;
  }
  const f32x4* xr = (const f32x4*)(xp + (size_t)rem * CD);
  f32x4 v[3];
#pragma unroll
  for (int i = 0; i < 3; ++i) v[i] = xr[lane + 64 * i];
  float sum = 0.f;
#pragma unroll
  for (int i = 0; i < 3; ++i)
#pragma unroll
    for (int j = 0; j < 4; ++j) sum += v[i][j];
#pragma unroll
  for (int m = 32; m >= 1; m >>= 1) sum += __shfl_xor(sum, m);
  const float mu = sum * (1.f / 768.f);
  float vs = 0.f;
#pragma unroll
  for (int i = 0; i < 3; ++i)
#pragma unroll
    for (int j = 0; j < 4; ++j) { float d = v[i][j] - mu; vs += d * d; }
#pragma unroll
  for (int m = 32; m >= 1; m >>= 1) vs += __shfl_xor(vs, m);
  const float rstd = rsqrtf(vs * (1.f / 768.f) + 1e-5f);
  const f32x4* gp = (const f32x4*)g;
  const f32x4* bp = (const f32x4*)b;
  bf16* orow = out + (size_t)row * CD;
#pragma unroll
  for (int i = 0; i < 3; ++i) {
    const int c4 = lane + 64 * i;
    f32x4 gg = gp[c4], bb = bp[c4];
    bf16x4 o;
#pragma unroll
    for (int j = 0; j < 4; ++j)
      o[j] = (bf16)((v[i][j] - mu) * rstd * gg[j] + bb[j]);
    *(bf16x4*)(orow + c4 * 4) = o;
  }
}

// ---------------------------------------------------------------------------
// FUSED: ys = xs + (ao0+ao1 bf16 split-K partials) + cross(a1);
// write ys (f32) + ln1(ys),ln2(ys) (bf16)
// ---------------------------------------------------------------------------
__global__ __launch_bounds__(256) void fuse_res_ln(
    const float* __restrict__ x0, const float* __restrict__ x1,
    const float* __restrict__ x2, const float* __restrict__ x3,
    const float* __restrict__ x4, const bf16* __restrict__ m01,
    const bf16* __restrict__ a, float* __restrict__ ys,
    const float* __restrict__ g1, const float* __restrict__ b1,
    const float* __restrict__ g2, const float* __restrict__ b2,
    bf16* __restrict__ o1, bf16* __restrict__ o2) {
  const int w = threadIdx.x >> 6, lane = threadIdx.x & 63;
  const int row = blockIdx.x * 4 + w;
  const int s = row >> 11, rem = row & 2047;
  const float* xp;
  switch (s) {
    case 0: xp = x0; break; case 1: xp = x1; break; case 2: xp = x2; break;
    case 3: xp = x3; break; default: xp = x4; break;
  }
  const f32x4* xr = (const f32x4*)(xp + (size_t)rem * CD);
  const bf16* p0 = m01 + (size_t)row * CD;
  const bf16* p1 = m01 + (size_t)TOK * CD + (size_t)row * CD;
  const bf16* am = a + (size_t)(row - 2048) * CD;
  const bf16* ap = a + (size_t)(row + 2048) * CD;
  f32x4 v[3];
#pragma unroll
  for (int i = 0; i < 3; ++i) {
    const int c4 = lane + 64 * i;
    f32x4 t = xr[c4] + b4tof(p0 + c4 * 4) + b4tof(p1 + c4 * 4);
    if (s > 0) t += b4tof(am + c4 * 4);
    if (s < 4) t += b4tof(ap + c4 * 4);
    v[i] = t;
  }
  f32x4* yr = (f32x4*)(ys + (size_t)row * CD);
#pragma unroll
  for (int i = 0; i < 3; ++i) yr[lane + 64 * i] = v[i];

  float sum = 0.f;
#pragma unroll
  for (int i = 0; i < 3; ++i)
#pragma unroll
    for (int j = 0; j < 4; ++j) sum += v[i][j];
#pragma unroll
  for (int m = 32; m >= 1; m >>= 1) sum += __shfl_xor(sum, m);
  const float mu = sum * (1.f / 768.f);
  float vs = 0.f;
#pragma unroll
  for (int i = 0; i < 3; ++i)
#pragma unroll
    for (int j = 0; j < 4; ++j) { float d = v[i][j] - mu; vs += d * d; }
#pragma unroll
  for (int m = 32; m >= 1; m >>= 1) vs += __shfl_xor(vs, m);
  const float rstd = rsqrtf(vs * (1.f / 768.f) + 1e-5f);
  bf16* r1 = o1 + (size_t)row * CD;
  bf16* r2 = o2 + (size_t)row * CD;
#pragma unroll
  for (int i = 0; i < 3; ++i) {
    const int c4 = lane + 64 * i;
    f32x4 gg1 = ((const f32x4*)g1)[c4], bb1 = ((const f32x4*)b1)[c4];
    f32x4 gg2 = ((const f32x4*)g2)[c4], bb2 = ((const f32x4*)b2)[c4];
    bf16x4 oa, ob;
#pragma unroll
    for (int j = 0; j < 4; ++j) {
      float n = (v[i][j] - mu) * rstd;
      oa[j] = (bf16)(n * gg1[j] + bb1[j]);
      ob[j] = (bf16)(n * gg2[j] + bb2[j]);
    }
    *(bf16x4*)(r1 + c4 * 4) = oa;
    *(bf16x4*)(r2 + c4 * 4) = ob;
  }
}

// ---------------------------------------------------------------------------
// GEMM 256x256, BK=32, 4 waves (2M x 2N), wave tile 128x128 (64 MFMA/wave).
// Rationale (R6 post-mortem): LDS read pipe is per-CU; at 128x64/wave the CU
// does ~2300 cyc of ds_read_b128 vs ~2480 cyc MFMA per tile, serialized ->
// ~21% MfmaUtil invariant across schedules. FLOP/LDS-byte = Mw*Nw/(Mw+Nw):
// 128x128 -> 64 (vs 42.7), LDS 768 cyc vs MFMA 1242 cyc -> ~62% even serial.
// Regs ~360/wave -> 1 wave/SIMD (launch_bounds(256,1), no spill at <=512).
// Zero TLP compensated by: triple-buffered LDS (96 KB), distance-2 prefetch,
// ONE raw s_barrier per tile, counted vmcnt(8) placed AFTER the MFMA block.
// Swizzle: 16B chunk ^= (row>>1)&3 on BOTH global source and ds_read.
// Optional split-K (kp = wg/bpk; bias only kp==0; out offset kp*kpstride).
// EPI: 0 = f32 store, 1 = bf16 store, 2 = fast-GELU -> bf16 store
// ---------------------------------------------------------------------------
template <int EPI>
__global__ __launch_bounds__(256, 1) void gemm256(
    const bf16* __restrict__ A, const bf16* __restrict__ Bt,
    const float* __restrict__ bias, void* __restrict__ Cout, int N, int Klen,
    int ldk, int nbn, int bpk, size_t kpstride) {
  __shared__ bf16 As[3][8192];  // [buf][256 rows][32 k]
  __shared__ bf16 Bs[3][8192];
  const int t = threadIdx.x, lane = t & 63, w = t >> 6;
  const int wm = w >> 1, wn = w & 1;

  // bijective XCD-chunked remap (gridDim.x % 8 == 0 by construction)
  const int chunkg = gridDim.x >> 3;
  const int wg = (blockIdx.x & 7) * chunkg + (blockIdx.x >> 3);
  const int kp = wg / bpk, rem = wg % bpk;
  const int bm = rem / nbn, bn = rem % nbn;

  f32x4 acc[8][8] = {};

  // staging: thread t covers rows 64i + (t>>2), chunk t&3; per issue the
  // 256 threads cover 64 rows x 32 elem = 2048 elements; wave base is
  // w*512 elements (64 lanes x 16B). [R7 bug was i*4096 + w*1024.]
  // source pre-swizzle: global chunk = (t&3) ^ ((row>>1)&3).
  const int srow = t >> 2;
  const int scol = ((t & 3) ^ ((srow >> 1) & 3)) << 3;
  const size_t koff = (size_t)kp * Klen;
  const bf16* Ab = A + (size_t)(bm * 256 + srow) * ldk + koff + scol;
  const bf16* Bb = Bt + (size_t)(bn * 256 + srow) * ldk + koff + scol;
  const size_t r64 = (size_t)64 * ldk;

  auto stage = [&](int buf, int kt) {
    const bf16* ga = Ab + (size_t)kt * 32;
    const bf16* gb = Bb + (size_t)kt * 32;
#pragma unroll
    for (int i = 0; i < 4; ++i)
      gload16(ga + i * r64, &As[buf][i * 2048 + w * 512]);
#pragma unroll
    for (int i = 0; i < 4; ++i)
      gload16(gb + i * r64, &Bs[buf][i * 2048 + w * 512]);
  };

  // fragment read constants: swizzle key (row>>1)&3 == (lane>>1)&3 for all
  // frag rows (wm*128, wn*128, m_*16 leave bits 1-2 of row untouched)
  const int arow = wm * 128 + (lane & 15);
  const int brow = wn * 128 + (lane & 15);
  const int achn = (((lane >> 4) ^ ((lane >> 1) & 3)) << 3);

  // prologue: tiles 0,1 into bufs 0,1
  stage(0, 0);
  stage(1, 1);
  asm volatile("s_waitcnt vmcnt(8)" ::: "memory");  // tile 0 landed
  __builtin_amdgcn_s_barrier();

  const int NT = Klen >> 5;
  bf16x8 af[8], bfr[8];
  int buf = 0;

  for (int kt = 0; kt < NT; ++kt) {
    // read all frags of tile kt (tile kt landed: gated at end of prev iter)
#pragma unroll
    for (int m_ = 0; m_ < 8; ++m_)
      af[m_] = *(const bf16x8*)&As[buf][(arow + m_ * 16) * 32 + achn];
#pragma unroll
    for (int n_ = 0; n_ < 8; ++n_)
      bfr[n_] = *(const bf16x8*)&Bs[buf][(brow + n_ * 16) * 32 + achn];
    asm volatile("s_waitcnt lgkmcnt(0)" ::: "memory");  // my reads done
    __builtin_amdgcn_s_barrier();  // all waves done reading buf[kt-1..kt]
    // stage tile kt+2 into buf[(kt+2)%3] (= tile kt-1's buffer, safe now);
    // DMA overlaps the MFMA block below.
    const int nbuf = (buf + 2 >= 3) ? buf - 1 : buf + 2;
    if (kt + 2 < NT) stage(nbuf, kt + 2);
    __builtin_amdgcn_s_setprio(1);
#pragma unroll
    for (int m_ = 0; m_ < 8; ++m_)
#pragma unroll
      for (int n_ = 0; n_ < 8; ++n_)
        acc[m_][n_] = mfma16(af[m_], bfr[n_], acc[m_][n_]);
    __builtin_amdgcn_s_setprio(0);
    // gate for NEXT iteration's reads: tile kt+1 must have landed.
    if (kt + 2 < NT)
      asm volatile("s_waitcnt vmcnt(8)" ::: "memory");  // kt+2 still in flight
    else
      asm volatile("s_waitcnt vmcnt(0)" ::: "memory");
    buf = (buf + 1 >= 3) ? 0 : buf + 1;
  }

  // epilogue (bias only on kp==0 so split-K partials sum correctly)
#pragma unroll
  for (int m_ = 0; m_ < 8; ++m_) {
    const int grow0 = bm * 256 + wm * 128 + m_ * 16 + (lane >> 4) * 4;
#pragma unroll
    for (int n_ = 0; n_ < 8; ++n_) {
      const int gcol = bn * 256 + wn * 128 + n_ * 16 + (lane & 15);
      const float bv = (kp == 0) ? bias[gcol] : 0.f;
#pragma unroll
      for (int r = 0; r < 4; ++r) {
        float v = acc[m_][n_][r] + bv;
        if (EPI == 2) v = fast_gelu(v);
        const size_t idx = (size_t)(grow0 + r) * N + gcol + kp * kpstride;
        if (EPI == 0) ((float*)Cout)[idx] = v;
        else ((bf16*)Cout)[idx] = (bf16)v;
      }
    }
  }
}

// ---------------------------------------------------------------------------
// Flash attention v2 — swapped-operand 32x32 MFMA, in-register softmax.
// ---------------------------------------------------------------------------
__global__ __launch_bounds__(256, 3) void attn_v2(
    const bf16* __restrict__ qkv, bf16* __restrict__ obuf) {
  __shared__ bf16 Ks[2][4096];
  __shared__ bf16 Vt[2][4096];
  const int t = threadIdx.x, lane = t & 63, w = t >> 6;
  const int g = lane >> 5, q32 = lane & 31, rq7 = q32 & 7;

  const int xcd = blockIdx.x & 7, slot = blockIdx.x >> 3;
  const int work = xcd * 120 + slot;
  const int sbh = work >> 3, qt = work & 7;
  const int sb = sbh / NH, h = sbh % NH;
  const size_t tokbase = (size_t)sb * SEQ;
  const int qoff = h * 64, koff = CD + h * 64, voff = 2 * CD + h * 64;

  const int qrow = qt * 128 + w * 32 + q32;
  bf16x8 qf[4];
  {
    const bf16* qp = qkv + (tokbase + qrow) * NQKV + qoff + g * 8;
#pragma unroll
    for (int kd = 0; kd < 4; ++kd) {
      bf16x8 v = *(const bf16x8*)(qp + kd * 16);
#pragma unroll
      for (int j = 0; j < 8; ++j) v[j] = (bf16)((float)v[j] * 0.125f);
      qf[kd] = v;
    }
  }

  const int skv1 = t >> 3, sc1 = (t & 7) ^ (skv1 & 7);
  const int skv2 = (t + 256) >> 3, sc2 = (t & 7) ^ (skv2 & 7);
  const int vkv0 = 2 * (t & 31);
  const int vd0 = 8 * (t >> 5);
  const int c0 = (vkv0 & 51) | ((vkv0 & 4) << 1) | ((vkv0 & 8) >> 1);
  const int vchunk = c0 >> 3, vsub = c0 & 7;
  const bf16* kbase = qkv + tokbase * NQKV + koff;
  const bf16* vbase = qkv + tokbase * NQKV + voff;

  {
    const bf16* kb0 = kbase;
    gload16(kb0 + (size_t)skv1 * NQKV + sc1 * 8, &Ks[0][w * 512]);
    gload16(kb0 + (size_t)skv2 * NQKV + sc2 * 8, &Ks[0][2048 + w * 512]);
    const bf16* vp = vbase + (size_t)vkv0 * NQKV + vd0;
    bf16x8 r0 = *(const bf16x8*)vp;
    bf16x8 r1 = *(const bf16x8*)(vp + NQKV);
#pragma unroll
    for (int j = 0; j < 8; ++j) {
      const int d = vd0 + j;
      *(unsigned*)&Vt[0][d * 64 + ((vchunk ^ j) << 3) + vsub] =
          pack2(r0[j], r1[j]);
    }
  }
  __syncthreads();

  float m_run = -1e30f, l_run = 0.f;
  f32x16 oT0 = {}, oT1 = {};
  int cur = 0;

  for (int kt = 0; kt < 16; ++kt) {
    bf16x8 nv0, nv1;
    if (kt < 15) {
      const bf16* vp = vbase + (size_t)((kt + 1) * 64 + vkv0) * NQKV + vd0;
      nv0 = *(const bf16x8*)vp;
      nv1 = *(const bf16x8*)(vp + NQKV);
      const bf16* kb0 = kbase + (size_t)(kt + 1) * 64 * NQKV;
      gload16(kb0 + (size_t)skv1 * NQKV + sc1 * 8, &Ks[cur ^ 1][w * 512]);
      gload16(kb0 + (size_t)skv2 * NQKV + sc2 * 8,
              &Ks[cur ^ 1][2048 + w * 512]);
    }

    f32x16 sT0 = {}, sT1 = {};
#pragma unroll
    for (int kd = 0; kd < 4; ++kd) {
      bf16x8 kf0 =
          *(const bf16x8*)&Ks[cur][q32 * 64 + (((2 * kd + g) ^ rq7) << 3)];
      bf16x8 kf1 = *(const bf16x8*)&Ks[cur][(32 + q32) * 64 +
                                            (((2 * kd + g) ^ rq7) << 3)];
      sT0 = mfma32(kf0, qf[kd], sT0);
      sT1 = mfma32(kf1, qf[kd], sT1);
    }

    float mt = sT0[0];
#pragma unroll
    for (int r = 1; r < 16; ++r) mt = fmaxf(mt, sT0[r]);
#pragma unroll
    for (int r = 0; r < 16; ++r) mt = fmaxf(mt, sT1[r]);
    mt = fmaxf(mt, __shfl_xor(mt, 32));
    const float mnew = fmaxf(m_run, mt);
    const float alpha = __expf(m_run - mnew);
    m_run = mnew;
    float rs = 0.f;
#pragma unroll
    for (int r = 0; r < 16; ++r) {
      sT0[r] = __expf(sT0[r] - mnew);
      rs += sT0[r];
    }
#pragma unroll
    for (int r = 0; r < 16; ++r) {
      sT1[r] = __expf(sT1[r] - mnew);
      rs += sT1[r];
    }
    rs += __shfl_xor(rs, 32);
    l_run = l_run * alpha + rs;
#pragma unroll
    for (int r = 0; r < 16; ++r) { oT0[r] *= alpha; oT1[r] *= alpha; }

    bf16x8 pa[4];
#pragma unroll
    for (int hh = 0; hh < 2; ++hh)
#pragma unroll
      for (int j = 0; j < 8; ++j) {
        pa[hh][j] = (bf16)sT0[8 * hh + j];
        pa[2 + hh][j] = (bf16)sT1[8 * hh + j];
      }

#pragma unroll
    for (int ks = 0; ks < 4; ++ks) {
      bf16x8 vf0 =
          *(const bf16x8*)&Vt[cur][q32 * 64 + (((2 * ks + g) ^ rq7) << 3)];
      bf16x8 vf1 = *(const bf16x8*)&Vt[cur][(32 + q32) * 64 +
                                            (((2 * ks + g) ^ rq7) << 3)];
      oT0 = mfma32(vf0, pa[ks], oT0);
      oT1 = mfma32(vf1, pa[ks], oT1);
    }

    if (kt < 15) {
#pragma unroll
      for (int j = 0; j < 8; ++j) {
        const int d = vd0 + j;
        *(unsigned*)&Vt[cur ^ 1][d * 64 + ((vchunk ^ j) << 3) + vsub] =
            pack2(nv0[j], nv1[j]);
      }
    }
    __syncthreads();
    cur ^= 1;
  }

  const float rl = 1.f / l_run;
  bf16* orow = obuf + (tokbase + qrow) * CD + h * 64;
#pragma unroll
  for (int m = 0; m < 4; ++m) {
    bf16x4 o0, o1;
#pragma unroll
    for (int r = 0; r < 4; ++r) {
      o0[r] = (bf16)(oT0[4 * m + r] * rl);
      o1[r] = (bf16)(oT1[4 * m + r] * rl);
    }
    *(bf16x4*)(orow + 8 * m + 4 * g) = o0;
    *(bf16x4*)(orow + 32 + 8 * m + 4 * g) = o1;
  }
}

// ---------------------------------------------------------------------------
// Adapter: out = ((X@dw+db)@mw+mb)@uw+ub ; X bf16 [TOK][768], out bf16.
// ---------------------------------------------------------------------------
__global__ __launch_bounds__(256) void adapter_kernel(
    const bf16* __restrict__ X, const float* __restrict__ dw,
    const float* __restrict__ db, const float* __restrict__ mw,
    const float* __restrict__ mb, const float* __restrict__ uw,
    const float* __restrict__ ub, bf16* __restrict__ out) {
  const int tok = blockIdx.x * 4 + (threadIdx.x >> 6);
  const int lane = threadIdx.x & 63;
  const bf16* xr = X + (size_t)tok * CD;
  float xv[12];
#pragma unroll
  for (int i = 0; i < 12; ++i) xv[i] = (float)xr[lane + 64 * i];
  float h1[8] = {0, 0, 0, 0, 0, 0, 0, 0};
#pragma unroll
  for (int i = 0; i < 12; ++i) {
    const f32x4* dr = (const f32x4*)(dw + (size_t)(lane + 64 * i) * 8);
    f32x4 d0 = dr[0], d1 = dr[1];
#pragma unroll
    for (int j = 0; j < 4; ++j) {
      h1[j] += xv[i] * d0[j];
      h1[4 + j] += xv[i] * d1[j];
    }
  }
#pragma unroll
  for (int m = 1; m < 64; m <<= 1)
#pragma unroll
    for (int j = 0; j < 8; ++j) h1[j] += __shfl_xor(h1[j], m);
#pragma unroll
  for (int j = 0; j < 8; ++j) h1[j] += db[j];
  float h2[8];
#pragma unroll
  for (int k = 0; k < 8; ++k) {
    float v = mb[k];
#pragma unroll
    for (int j = 0; j < 8; ++j) v += h1[j] * mw[j * 8 + k];
    h2[k] = v;
  }
#pragma unroll
  for (int i = 0; i < 12; ++i) {
    const int c = lane + 64 * i;
    float v = ub[c];
#pragma unroll
    for (int k = 0; k < 8; ++k) v += h2[k] * uw[k * CD + c];
    out[(size_t)tok * CD + c] = (bf16)v;
  }
}

// ---------------------------------------------------------------------------
// Final: z[s] = ys[s] + m0[s] + m1[s] + (s>0 ? a[s-1] : 0) + (s<4 ? a[s+1] : 0)
// ---------------------------------------------------------------------------
__global__ __launch_bounds__(256) void cross_residual(
    const float* __restrict__ ys, const bf16* __restrict__ m01,
    const bf16* __restrict__ a, float* __restrict__ out) {
  const int s = blockIdx.y;
  const size_t i = (size_t)blockIdx.x * 256 + threadIdx.x;  // group-of-4 index
  const size_t spitch = (size_t)2048 * 768 / 4;
  const size_t sb = (size_t)s * spitch;
  const size_t mstride = (size_t)TOK * CD / 4;
  f32x4 v = ((const f32x4*)ys)[sb + i];
  v += b4tof(m01 + (sb + i) * 4);
  v += b4tof(m01 + (mstride + sb + i) * 4);
  if (s > 0) v += b4tof(a + (sb - spitch + i) * 4);
  if (s < 4) v += b4tof(a + (sb + spitch + i) * 4);
  ((f32x4*)out)[sb + i] = v;
}

// ---------------------------------------------------------------------------
// workspace layout (bytes; ~203 MB)
// ---------------------------------------------------------------------------
#define OFF_WTQKV  ((size_t)0)           // bf16 [2304][768]
#define OFF_WTPROJ ((size_t)3538944)     // bf16 [768][768]
#define OFF_WTFC1  ((size_t)4718592)     // bf16 [3072][768]
#define OFF_WTFC2  ((size_t)9437184)     // bf16 [768][3072]
#define OFF_N1     ((size_t)14155776)    // bf16 [10240][768]; later ln1(ys)
#define OFF_BIG    ((size_t)29884416)    // bf16 qkv [10240][2304]; later h
#define OFF_OBUF   ((size_t)77070336)    // bf16 o [10240][768]
#define OFF_AOM    ((size_t)92798976)    // bf16 partial pairs (proj, then fc2)
#define OFF_A12    ((size_t)124256256)   // bf16 [10240][768]: a1, later a2
#define OFF_YS     ((size_t)155713536)   // f32 [10240][768]
#define OFF_L2Y    ((size_t)187170816)   // bf16 [10240][768]

extern "C" void kernel_launch(void* const* d_in, const int* in_sizes, int n_in,
                              void* d_out, int out_size, void* d_ws,
                              size_t ws_size, hipStream_t stream) {
  const float* x0 = (const float*)d_in[0];
  const float* x1 = (const float*)d_in[1];
  const float* x2 = (const float*)d_in[2];
  const float* x3 = (const float*)d_in[3];
  const float* x4 = (const float*)d_in[4];
  const float* ln1_g = (const float*)d_in[5];
  const float* ln1_b = (const float*)d_in[6];
  const float* ln2_g = (const float*)d_in[7];
  const float* ln2_b = (const float*)d_in[8];
  const float* qkv_w = (const float*)d_in[9];
  const float* qkv_b = (const float*)d_in[10];
  const float* proj_w = (const float*)d_in[11];
  const float* proj_b = (const float*)d_in[12];
  const float* fc1_w = (const float*)d_in[13];
  const float* fc1_b = (const float*)d_in[14];
  const float* fc2_w = (const float*)d_in[15];
  const float* fc2_b = (const float*)d_in[16];
  const float* at_dw = (const float*)d_in[17];
  const float* at_db = (const float*)d_in[18];
  const float* at_mw = (const float*)d_in[19];
  const float* at_mb = (const float*)d_in[20];
  const float* at_uw = (const float*)d_in[21];
  const float* at_ub = (const float*)d_in[22];
  const float* a2_dw = (const float*)d_in[23];
  const float* a2_db = (const float*)d_in[24];
  const float* a2_mw = (const float*)d_in[25];
  const float* a2_mb = (const float*)d_in[26];
  const float* a2_uw = (const float*)d_in[27];
  const float* a2_ub = (const float*)d_in[28];

  char* ws = (char*)d_ws;
  bf16* wt_qkv = (bf16*)(ws + OFF_WTQKV);
  bf16* wt_proj = (bf16*)(ws + OFF_WTPROJ);
  bf16* wt_fc1 = (bf16*)(ws + OFF_WTFC1);
  bf16* wt_fc2 = (bf16*)(ws + OFF_WTFC2);
  bf16* n1 = (bf16*)(ws + OFF_N1);
  bf16* qkvb = (bf16*)(ws + OFF_BIG);
  bf16* obuf = (bf16*)(ws + OFF_OBUF);
  bf16* mbuf = (bf16*)(ws + OFF_AOM);  // split-K bf16 partial pair
  bf16* a12 = (bf16*)(ws + OFF_A12);
  float* ysb = (float*)(ws + OFF_YS);
  bf16* l2y = (bf16*)(ws + OFF_L2Y);

  const dim3 b256(256);

  // 1. weight convert+transpose -> bf16 [N][K]
  transpose_to_bf16<<<dim3(72, 24), b256, 0, stream>>>(qkv_w, wt_qkv, 768, 2304);
  transpose_to_bf16<<<dim3(24, 24), b256, 0, stream>>>(proj_w, wt_proj, 768, 768);
  transpose_to_bf16<<<dim3(96, 24), b256, 0, stream>>>(fc1_w, wt_fc1, 768, 3072);
  transpose_to_bf16<<<dim3(24, 96), b256, 0, stream>>>(fc2_w, wt_fc2, 3072, 768);

  // 2. n1 = LN(xs)  (bf16)
  ln5_kernel<<<2560, b256, 0, stream>>>(x0, x1, x2, x3, x4, ln1_g, ln1_b, n1);

  // 3. qkv = n1 @ qkv_w + qkv_b  (bf16)   grid 40*9=360
  gemm256<1><<<360, b256, 0, stream>>>(n1, wt_qkv, qkv_b, qkvb, NQKV, 768, 768,
                                       9, 360, 0);

  // 4. a1 = adapter(n1)  (bf16)
  adapter_kernel<<<2560, b256, 0, stream>>>(n1, at_dw, at_db, at_mw, at_mb,
                                            at_uw, at_ub, a12);

  // 5. attention -> o (bf16)
  attn_v2<<<960, b256, 0, stream>>>(qkvb, obuf);

  // 6. ao = o @ proj_w + proj_b  — split-K=2, bf16 partials (grid 240)
  gemm256<1><<<240, b256, 0, stream>>>(obuf, wt_proj, proj_b, mbuf, CD, 384,
                                       768, 3, 120, (size_t)TOK * CD);

  // 7+8. ys = xs + (ao0+ao1) + cross(a1); ln1(ys)->n1, ln2(ys)->l2y
  fuse_res_ln<<<2560, b256, 0, stream>>>(x0, x1, x2, x3, x4, mbuf, a12, ysb,
                                         ln1_g, ln1_b, ln2_g, ln2_b, n1, l2y);

  // 9. a2 = adapter(ln1(ys))  (bf16, overwrites a1)
  adapter_kernel<<<2560, b256, 0, stream>>>(n1, a2_dw, a2_db, a2_mw, a2_mb,
                                            a2_uw, a2_ub, a12);

  // 10. h = gelu(ln2(ys) @ fc1_w + fc1_b)  (bf16)  grid 40*12=480
  gemm256<2><<<480, b256, 0, stream>>>(l2y, wt_fc1, fc1_b, qkvb, NHID, 768,
                                       768, 12, 480, 0);

  // 11. m = h @ fc2_w + fc2_b  — split-K=2, bf16 partials (grid 240)
  gemm256<1><<<240, b256, 0, stream>>>(qkvb, wt_fc2, fc2_b, mbuf, CD, 1536,
                                       3072, 3, 120, (size_t)TOK * CD);

  // 12. z = ys + (m0+m1) + cross(a2) -> d_out
  cross_residual<<<dim3(1536, 5), b256, 0, stream>>>(ysb, mbuf, a12,
                                                     (float*)d_out);
}

// Round 9
// 428.710 us; speedup vs baseline: 1.0165x; 1.0165x over previous
//
#include <hip/hip_runtime.h>
#include <math.h>

// ---------------------------------------------------------------------------
// Shapes: 5 streams x B=2 x N=1024 x C=768; H=12 heads x D=64; AD=8; HID=3072
// TOK = 5*2*1024 = 10240 rows everywhere.
// ---------------------------------------------------------------------------
typedef __bf16 bf16;
typedef __attribute__((ext_vector_type(8))) __bf16 bf16x8;
typedef __attribute__((ext_vector_type(4))) __bf16 bf16x4;
typedef __attribute__((ext_vector_type(4))) float f32x4;
typedef __attribute__((ext_vector_type(16))) float f32x16;

#define TOK   10240
#define CD    768
#define NQKV  2304
#define NHID  3072
#define SEQ   1024
#define NH    12

__device__ __forceinline__ f32x4 mfma16(bf16x8 a, bf16x8 b, f32x4 c) {
  return __builtin_amdgcn_mfma_f32_16x16x32_bf16(a, b, c, 0, 0, 0);
}
__device__ __forceinline__ f32x16 mfma32(bf16x8 a, bf16x8 b, f32x16 c) {
  return __builtin_amdgcn_mfma_f32_32x32x16_bf16(a, b, c, 0, 0, 0);
}

// async global->LDS, 16B per lane. LDS dest must be wave-uniform base;
// HW writes at base + lane*16. Global src is per-lane.
__device__ __forceinline__ void gload16(const void* g, void* l) {
  __builtin_amdgcn_global_load_lds(
      (const __attribute__((address_space(1))) void*)g,
      (__attribute__((address_space(3))) void*)l, 16, 0, 0);
}

__device__ __forceinline__ unsigned pack2(bf16 a, bf16 b) {
  union { unsigned short u[2]; unsigned v; } x;
  x.u[0] = __builtin_bit_cast(unsigned short, a);
  x.u[1] = __builtin_bit_cast(unsigned short, b);
  return x.v;
}

__device__ __forceinline__ f32x4 b4tof(const bf16* p) {
  bf16x4 v = *(const bf16x4*)p;
  f32x4 r;
#pragma unroll
  for (int j = 0; j < 4; ++j) r[j] = (float)v[j];
  return r;
}

// tanh-approx GELU (abs err ~3e-3, fine vs 0.11 threshold); __expf is HW exp
__device__ __forceinline__ float fast_gelu(float v) {
  float u = 0.7978845608f * (v + 0.044715f * v * v * v);
  float e = __expf(fminf(2.f * u, 30.f));
  return 0.5f * v * (1.f + (e - 1.f) / (e + 1.f));
}

// ---------------------------------------------------------------------------
// Weight convert+transpose: in [K][N] f32 -> out [N][K] bf16
// ---------------------------------------------------------------------------
__global__ __launch_bounds__(256) void transpose_to_bf16(
    const float* __restrict__ in, bf16* __restrict__ out, int K, int N) {
  __shared__ float tile[32][33];
  const int bn = blockIdx.x * 32, bk = blockIdx.y * 32;
  const int r = threadIdx.x >> 5, c = threadIdx.x & 31;
#pragma unroll
  for (int i = 0; i < 4; ++i)
    tile[r + 8 * i][c] = in[(size_t)(bk + r + 8 * i) * N + bn + c];
  __syncthreads();
#pragma unroll
  for (int i = 0; i < 4; ++i)
    out[(size_t)(bn + r + 8 * i) * K + bk + c] = (bf16)tile[c][r + 8 * i];
}

// ---------------------------------------------------------------------------
// LN over 5 stacked stream inputs -> bf16 [TOK][768]
// ---------------------------------------------------------------------------
__global__ __launch_bounds__(256) void ln5_kernel(
    const float* __restrict__ x0, const float* __restrict__ x1,
    const float* __restrict__ x2, const float* __restrict__ x3,
    const float* __restrict__ x4, const float* __restrict__ g,
    const float* __restrict__ b, bf16* __restrict__ out) {
  const int w = threadIdx.x >> 6, lane = threadIdx.x & 63;
  const int row = blockIdx.x * 4 + w;
  const int s = row >> 11, rem = row & 2047;
  const float* xp;
  switch (s) {
    case 0: xp = x0; break; case 1: xp = x1; break; case 2: xp = x2; break;
    case 3: xp = x3; break; default: xp = x4; break;
  }
  const f32x4* xr = (const f32x4*)(xp + (size_t)rem * CD);
  f32x4 v[3];
#pragma unroll
  for (int i = 0; i < 3; ++i) v[i] = xr[lane + 64 * i];
  float sum = 0.f;
#pragma unroll
  for (int i = 0; i < 3; ++i)
#pragma unroll
    for (int j = 0; j < 4; ++j) sum += v[i][j];
#pragma unroll
  for (int m = 32; m >= 1; m >>= 1) sum += __shfl_xor(sum, m);
  const float mu = sum * (1.f / 768.f);
  float vs = 0.f;
#pragma unroll
  for (int i = 0; i < 3; ++i)
#pragma unroll
    for (int j = 0; j < 4; ++j) { float d = v[i][j] - mu; vs += d * d; }
#pragma unroll
  for (int m = 32; m >= 1; m >>= 1) vs += __shfl_xor(vs, m);
  const float rstd = rsqrtf(vs * (1.f / 768.f) + 1e-5f);
  const f32x4* gp = (const f32x4*)g;
  const f32x4* bp = (const f32x4*)b;
  bf16* orow = out + (size_t)row * CD;
#pragma unroll
  for (int i = 0; i < 3; ++i) {
    const int c4 = lane + 64 * i;
    f32x4 gg = gp[c4], bb = bp[c4];
    bf16x4 o;
#pragma unroll
    for (int j = 0; j < 4; ++j)
      o[j] = (bf16)((v[i][j] - mu) * rstd * gg[j] + bb[j]);
    *(bf16x4*)(orow + c4 * 4) = o;
  }
}

// ---------------------------------------------------------------------------
// FUSED: ys = xs + (ao0+ao1 bf16 split-K partials) + cross(a1);
// write ys (f32) + ln1(ys),ln2(ys) (bf16)
// ---------------------------------------------------------------------------
__global__ __launch_bounds__(256) void fuse_res_ln(
    const float* __restrict__ x0, const float* __restrict__ x1,
    const float* __restrict__ x2, const float* __restrict__ x3,
    const float* __restrict__ x4, const bf16* __restrict__ m01,
    const bf16* __restrict__ a, float* __restrict__ ys,
    const float* __restrict__ g1, const float* __restrict__ b1,
    const float* __restrict__ g2, const float* __restrict__ b2,
    bf16* __restrict__ o1, bf16* __restrict__ o2) {
  const int w = threadIdx.x >> 6, lane = threadIdx.x & 63;
  const int row = blockIdx.x * 4 + w;
  const int s = row >> 11, rem = row & 2047;
  const float* xp;
  switch (s) {
    case 0: xp = x0; break; case 1: xp = x1; break; case 2: xp = x2; break;
    case 3: xp = x3; break; default: xp = x4; break;
  }
  const f32x4* xr = (const f32x4*)(xp + (size_t)rem * CD);
  const bf16* p0 = m01 + (size_t)row * CD;
  const bf16* p1 = m01 + (size_t)TOK * CD + (size_t)row * CD;
  const bf16* am = a + (size_t)(row - 2048) * CD;
  const bf16* ap = a + (size_t)(row + 2048) * CD;
  f32x4 v[3];
#pragma unroll
  for (int i = 0; i < 3; ++i) {
    const int c4 = lane + 64 * i;
    f32x4 t = xr[c4] + b4tof(p0 + c4 * 4) + b4tof(p1 + c4 * 4);
    if (s > 0) t += b4tof(am + c4 * 4);
    if (s < 4) t += b4tof(ap + c4 * 4);
    v[i] = t;
  }
  f32x4* yr = (f32x4*)(ys + (size_t)row * CD);
#pragma unroll
  for (int i = 0; i < 3; ++i) yr[lane + 64 * i] = v[i];

  float sum = 0.f;
#pragma unroll
  for (int i = 0; i < 3; ++i)
#pragma unroll
    for (int j = 0; j < 4; ++j) sum += v[i][j];
#pragma unroll
  for (int m = 32; m >= 1; m >>= 1) sum += __shfl_xor(sum, m);
  const float mu = sum * (1.f / 768.f);
  float vs = 0.f;
#pragma unroll
  for (int i = 0; i < 3; ++i)
#pragma unroll
    for (int j = 0; j < 4; ++j) { float d = v[i][j] - mu; vs += d * d; }
#pragma unroll
  for (int m = 32; m >= 1; m >>= 1) vs += __shfl_xor(vs, m);
  const float rstd = rsqrtf(vs * (1.f / 768.f) + 1e-5f);
  bf16* r1 = o1 + (size_t)row * CD;
  bf16* r2 = o2 + (size_t)row * CD;
#pragma unroll
  for (int i = 0; i < 3; ++i) {
    const int c4 = lane + 64 * i;
    f32x4 gg1 = ((const f32x4*)g1)[c4], bb1 = ((const f32x4*)b1)[c4];
    f32x4 gg2 = ((const f32x4*)g2)[c4], bb2 = ((const f32x4*)b2)[c4];
    bf16x4 oa, ob;
#pragma unroll
    for (int j = 0; j < 4; ++j) {
      float n = (v[i][j] - mu) * rstd;
      oa[j] = (bf16)(n * gg1[j] + bb1[j]);
      ob[j] = (bf16)(n * gg2[j] + bb2[j]);
    }
    *(bf16x4*)(r1 + c4 * 4) = oa;
    *(bf16x4*)(r2 + c4 * 4) = ob;
  }
}

// ---------------------------------------------------------------------------
// GEMM 256x256, BK=32, 8 waves (2M x 4N, wave tile 128x64), 64 KiB LDS.
// R8 post-mortem: the old loop forced {lgkmcnt(0); barrier} BETWEEN ds_reads
// and MFMAs -> LDS phase and MFMA phase fully serialized (measured per-tile
// cycles = exact serial sum; both co-resident blocks contend on the shared
// per-CU matrix pipe, so TLP can't recover it). New loop per K-tile kt:
//   { ds_read frags(kt)  [no drain — compiler emits partial lgkmcnt, so
//     ds_read latency hides under the MFMA block]
//     32 MFMA
//     vmcnt(0)   [counted in effect: only tile kt+1's 4 loads outstanding,
//                 issued one full tile earlier]
//     sched_barrier(0)   [rule #18: pin MFMAs/reads before the raw barrier]
//     s_barrier          [all waves consumed tile kt -> buffer reusable]
//     stage(kt+2 -> buf kt&1)  [DMA overlaps next tile's reads+MFMA] }
// Swizzle: 16B chunk ^= (row>>1)&3 on BOTH global source and ds_read.
// Optional split-K (kp = wg/bpk; bias only kp==0; out offset kp*kpstride).
// EPI: 0 = f32 store, 1 = bf16 store, 2 = fast-GELU -> bf16 store
// ---------------------------------------------------------------------------
template <int EPI>
__global__ __launch_bounds__(512, 2) void gemm256(
    const bf16* __restrict__ A, const bf16* __restrict__ Bt,
    const float* __restrict__ bias, void* __restrict__ Cout, int N, int Klen,
    int ldk, int nbn, int bpk, size_t kpstride) {
  __shared__ bf16 As[2][8192];  // [buf][256 rows][32 k]
  __shared__ bf16 Bs[2][8192];
  const int t = threadIdx.x, lane = t & 63, w = t >> 6;
  const int wm = w >> 2, wn = w & 3;

  // bijective XCD-chunked remap (gridDim.x % 8 == 0 by construction)
  const int chunkg = gridDim.x >> 3;
  const int wg = (blockIdx.x & 7) * chunkg + (blockIdx.x >> 3);
  const int kp = wg / bpk, rem = wg % bpk;
  const int bm = rem / nbn, bn = rem % nbn;

  f32x4 acc[8][4] = {};

  // staging: thread t covers LDS slot (row = t>>2 [+128 on 2nd issue],
  // chunk = t&3); source pre-swizzle chunk_g = (t&3) ^ ((row>>1)&3)
  // (the +128 doesn't touch row bits 1-2, so one scol serves both issues).
  const int srow = t >> 2;
  const int scol = ((t & 3) ^ ((srow >> 1) & 3)) << 3;
  const size_t koff = (size_t)kp * Klen;
  const bf16* Ab = A + (size_t)(bm * 256 + srow) * ldk + koff + scol;
  const bf16* Bb = Bt + (size_t)(bn * 256 + srow) * ldk + koff + scol;
  const size_t r128 = (size_t)128 * ldk;

  auto stage = [&](int buf, int kt) {
    const bf16* ga = Ab + (size_t)kt * 32;
    const bf16* gb = Bb + (size_t)kt * 32;
    gload16(ga, &As[buf][w * 512]);
    gload16(ga + r128, &As[buf][4096 + w * 512]);
    gload16(gb, &Bs[buf][w * 512]);
    gload16(gb + r128, &Bs[buf][4096 + w * 512]);
  };

  // fragment read constants: swizzle key (row>>1)&3 == (lane>>1)&3 for all
  // frag rows (wm*128, wn*64, m_*16 leave bits 1-2 of row untouched)
  const int arow = wm * 128 + (lane & 15);
  const int brow = wn * 64 + (lane & 15);
  const int achn = (((lane >> 4) ^ ((lane >> 1) & 3)) << 3);

  // prologue: tiles 0,1
  stage(0, 0);
  stage(1, 1);
  asm volatile("s_waitcnt vmcnt(4)" ::: "memory");  // tile 0 landed
  __builtin_amdgcn_s_barrier();

  const int NT = Klen >> 5;
  bf16x8 af[8], bfr[4];

  for (int kt = 0; kt < NT; ++kt) {
    const int buf = kt & 1;
    // frag reads (B first, then A) — NO drain: compiler interleaves the
    // dependent MFMAs below with partial lgkmcnt waits.
#pragma unroll
    for (int n_ = 0; n_ < 4; ++n_)
      bfr[n_] = *(const bf16x8*)&Bs[buf][(brow + n_ * 16) * 32 + achn];
#pragma unroll
    for (int m_ = 0; m_ < 8; ++m_)
      af[m_] = *(const bf16x8*)&As[buf][(arow + m_ * 16) * 32 + achn];
#pragma unroll
    for (int m_ = 0; m_ < 8; ++m_)
#pragma unroll
      for (int n_ = 0; n_ < 4; ++n_)
        acc[m_][n_] = mfma16(af[m_], bfr[n_], acc[m_][n_]);
    if (kt + 1 < NT) {
      // outstanding VMEM here = tile kt+1's 4 loads (issued one tile ago)
      asm volatile("s_waitcnt vmcnt(0)" ::: "memory");
      __builtin_amdgcn_sched_barrier(0);  // keep reads/MFMAs above s_barrier
      __builtin_amdgcn_s_barrier();       // all waves done with tile kt
      if (kt + 2 < NT) stage(buf, kt + 2);
    }
  }

  // epilogue (bias only on kp==0 so split-K partials sum correctly)
#pragma unroll
  for (int m_ = 0; m_ < 8; ++m_) {
    const int grow0 = bm * 256 + wm * 128 + m_ * 16 + (lane >> 4) * 4;
#pragma unroll
    for (int n_ = 0; n_ < 4; ++n_) {
      const int gcol = bn * 256 + wn * 64 + n_ * 16 + (lane & 15);
      const float bv = (kp == 0) ? bias[gcol] : 0.f;
#pragma unroll
      for (int r = 0; r < 4; ++r) {
        float v = acc[m_][n_][r] + bv;
        if (EPI == 2) v = fast_gelu(v);
        const size_t idx = (size_t)(grow0 + r) * N + gcol + kp * kpstride;
        if (EPI == 0) ((float*)Cout)[idx] = v;
        else ((bf16*)Cout)[idx] = (bf16)v;
      }
    }
  }
}

// ---------------------------------------------------------------------------
// Flash attention v2 — swapped-operand 32x32 MFMA, in-register softmax.
// ---------------------------------------------------------------------------
__global__ __launch_bounds__(256, 3) void attn_v2(
    const bf16* __restrict__ qkv, bf16* __restrict__ obuf) {
  __shared__ bf16 Ks[2][4096];
  __shared__ bf16 Vt[2][4096];
  const int t = threadIdx.x, lane = t & 63, w = t >> 6;
  const int g = lane >> 5, q32 = lane & 31, rq7 = q32 & 7;

  const int xcd = blockIdx.x & 7, slot = blockIdx.x >> 3;
  const int work = xcd * 120 + slot;
  const int sbh = work >> 3, qt = work & 7;
  const int sb = sbh / NH, h = sbh % NH;
  const size_t tokbase = (size_t)sb * SEQ;
  const int qoff = h * 64, koff = CD + h * 64, voff = 2 * CD + h * 64;

  const int qrow = qt * 128 + w * 32 + q32;
  bf16x8 qf[4];
  {
    const bf16* qp = qkv + (tokbase + qrow) * NQKV + qoff + g * 8;
#pragma unroll
    for (int kd = 0; kd < 4; ++kd) {
      bf16x8 v = *(const bf16x8*)(qp + kd * 16);
#pragma unroll
      for (int j = 0; j < 8; ++j) v[j] = (bf16)((float)v[j] * 0.125f);
      qf[kd] = v;
    }
  }

  const int skv1 = t >> 3, sc1 = (t & 7) ^ (skv1 & 7);
  const int skv2 = (t + 256) >> 3, sc2 = (t & 7) ^ (skv2 & 7);
  const int vkv0 = 2 * (t & 31);
  const int vd0 = 8 * (t >> 5);
  const int c0 = (vkv0 & 51) | ((vkv0 & 4) << 1) | ((vkv0 & 8) >> 1);
  const int vchunk = c0 >> 3, vsub = c0 & 7;
  const bf16* kbase = qkv + tokbase * NQKV + koff;
  const bf16* vbase = qkv + tokbase * NQKV + voff;

  {
    const bf16* kb0 = kbase;
    gload16(kb0 + (size_t)skv1 * NQKV + sc1 * 8, &Ks[0][w * 512]);
    gload16(kb0 + (size_t)skv2 * NQKV + sc2 * 8, &Ks[0][2048 + w * 512]);
    const bf16* vp = vbase + (size_t)vkv0 * NQKV + vd0;
    bf16x8 r0 = *(const bf16x8*)vp;
    bf16x8 r1 = *(const bf16x8*)(vp + NQKV);
#pragma unroll
    for (int j = 0; j < 8; ++j) {
      const int d = vd0 + j;
      *(unsigned*)&Vt[0][d * 64 + ((vchunk ^ j) << 3) + vsub] =
          pack2(r0[j], r1[j]);
    }
  }
  __syncthreads();

  float m_run = -1e30f, l_run = 0.f;
  f32x16 oT0 = {}, oT1 = {};
  int cur = 0;

  for (int kt = 0; kt < 16; ++kt) {
    bf16x8 nv0, nv1;
    if (kt < 15) {
      const bf16* vp = vbase + (size_t)((kt + 1) * 64 + vkv0) * NQKV + vd0;
      nv0 = *(const bf16x8*)vp;
      nv1 = *(const bf16x8*)(vp + NQKV);
      const bf16* kb0 = kbase + (size_t)(kt + 1) * 64 * NQKV;
      gload16(kb0 + (size_t)skv1 * NQKV + sc1 * 8, &Ks[cur ^ 1][w * 512]);
      gload16(kb0 + (size_t)skv2 * NQKV + sc2 * 8,
              &Ks[cur ^ 1][2048 + w * 512]);
    }

    f32x16 sT0 = {}, sT1 = {};
#pragma unroll
    for (int kd = 0; kd < 4; ++kd) {
      bf16x8 kf0 =
          *(const bf16x8*)&Ks[cur][q32 * 64 + (((2 * kd + g) ^ rq7) << 3)];
      bf16x8 kf1 = *(const bf16x8*)&Ks[cur][(32 + q32) * 64 +
                                            (((2 * kd + g) ^ rq7) << 3)];
      sT0 = mfma32(kf0, qf[kd], sT0);
      sT1 = mfma32(kf1, qf[kd], sT1);
    }

    float mt = sT0[0];
#pragma unroll
    for (int r = 1; r < 16; ++r) mt = fmaxf(mt, sT0[r]);
#pragma unroll
    for (int r = 0; r < 16; ++r) mt = fmaxf(mt, sT1[r]);
    mt = fmaxf(mt, __shfl_xor(mt, 32));
    const float mnew = fmaxf(m_run, mt);
    const float alpha = __expf(m_run - mnew);
    m_run = mnew;
    float rs = 0.f;
#pragma unroll
    for (int r = 0; r < 16; ++r) {
      sT0[r] = __expf(sT0[r] - mnew);
      rs += sT0[r];
    }
#pragma unroll
    for (int r = 0; r < 16; ++r) {
      sT1[r] = __expf(sT1[r] - mnew);
      rs += sT1[r];
    }
    rs += __shfl_xor(rs, 32);
    l_run = l_run * alpha + rs;
#pragma unroll
    for (int r = 0; r < 16; ++r) { oT0[r] *= alpha; oT1[r] *= alpha; }

    bf16x8 pa[4];
#pragma unroll
    for (int hh = 0; hh < 2; ++hh)
#pragma unroll
      for (int j = 0; j < 8; ++j) {
        pa[hh][j] = (bf16)sT0[8 * hh + j];
        pa[2 + hh][j] = (bf16)sT1[8 * hh + j];
      }

#pragma unroll
    for (int ks = 0; ks < 4; ++ks) {
      bf16x8 vf0 =
          *(const bf16x8*)&Vt[cur][q32 * 64 + (((2 * ks + g) ^ rq7) << 3)];
      bf16x8 vf1 = *(const bf16x8*)&Vt[cur][(32 + q32) * 64 +
                                            (((2 * ks + g) ^ rq7) << 3)];
      oT0 = mfma32(vf0, pa[ks], oT0);
      oT1 = mfma32(vf1, pa[ks], oT1);
    }

    if (kt < 15) {
#pragma unroll
      for (int j = 0; j < 8; ++j) {
        const int d = vd0 + j;
        *(unsigned*)&Vt[cur ^ 1][d * 64 + ((vchunk ^ j) << 3) + vsub] =
            pack2(nv0[j], nv1[j]);
      }
    }
    __syncthreads();
    cur ^= 1;
  }

  const float rl = 1.f / l_run;
  bf16* orow = obuf + (tokbase + qrow) * CD + h * 64;
#pragma unroll
  for (int m = 0; m < 4; ++m) {
    bf16x4 o0, o1;
#pragma unroll
    for (int r = 0; r < 4; ++r) {
      o0[r] = (bf16)(oT0[4 * m + r] * rl);
      o1[r] = (bf16)(oT1[4 * m + r] * rl);
    }
    *(bf16x4*)(orow + 8 * m + 4 * g) = o0;
    *(bf16x4*)(orow + 32 + 8 * m + 4 * g) = o1;
  }
}

// ---------------------------------------------------------------------------
// Adapter: out = ((X@dw+db)@mw+mb)@uw+ub ; X bf16 [TOK][768], out bf16.
// ---------------------------------------------------------------------------
__global__ __launch_bounds__(256) void adapter_kernel(
    const bf16* __restrict__ X, const float* __restrict__ dw,
    const float* __restrict__ db, const float* __restrict__ mw,
    const float* __restrict__ mb, const float* __restrict__ uw,
    const float* __restrict__ ub, bf16* __restrict__ out) {
  const int tok = blockIdx.x * 4 + (threadIdx.x >> 6);
  const int lane = threadIdx.x & 63;
  const bf16* xr = X + (size_t)tok * CD;
  float xv[12];
#pragma unroll
  for (int i = 0; i < 12; ++i) xv[i] = (float)xr[lane + 64 * i];
  float h1[8] = {0, 0, 0, 0, 0, 0, 0, 0};
#pragma unroll
  for (int i = 0; i < 12; ++i) {
    const f32x4* dr = (const f32x4*)(dw + (size_t)(lane + 64 * i) * 8);
    f32x4 d0 = dr[0], d1 = dr[1];
#pragma unroll
    for (int j = 0; j < 4; ++j) {
      h1[j] += xv[i] * d0[j];
      h1[4 + j] += xv[i] * d1[j];
    }
  }
#pragma unroll
  for (int m = 1; m < 64; m <<= 1)
#pragma unroll
    for (int j = 0; j < 8; ++j) h1[j] += __shfl_xor(h1[j], m);
#pragma unroll
  for (int j = 0; j < 8; ++j) h1[j] += db[j];
  float h2[8];
#pragma unroll
  for (int k = 0; k < 8; ++k) {
    float v = mb[k];
#pragma unroll
    for (int j = 0; j < 8; ++j) v += h1[j] * mw[j * 8 + k];
    h2[k] = v;
  }
#pragma unroll
  for (int i = 0; i < 12; ++i) {
    const int c = lane + 64 * i;
    float v = ub[c];
#pragma unroll
    for (int k = 0; k < 8; ++k) v += h2[k] * uw[k * CD + c];
    out[(size_t)tok * CD + c] = (bf16)v;
  }
}

// ---------------------------------------------------------------------------
// Final: z[s] = ys[s] + m0[s] + m1[s] + (s>0 ? a[s-1] : 0) + (s<4 ? a[s+1] : 0)
// ---------------------------------------------------------------------------
__global__ __launch_bounds__(256) void cross_residual(
    const float* __restrict__ ys, const bf16* __restrict__ m01,
    const bf16* __restrict__ a, float* __restrict__ out) {
  const int s = blockIdx.y;
  const size_t i = (size_t)blockIdx.x * 256 + threadIdx.x;  // group-of-4 index
  const size_t spitch = (size_t)2048 * 768 / 4;
  const size_t sb = (size_t)s * spitch;
  const size_t mstride = (size_t)TOK * CD / 4;
  f32x4 v = ((const f32x4*)ys)[sb + i];
  v += b4tof(m01 + (sb + i) * 4);
  v += b4tof(m01 + (mstride + sb + i) * 4);
  if (s > 0) v += b4tof(a + (sb - spitch + i) * 4);
  if (s < 4) v += b4tof(a + (sb + spitch + i) * 4);
  ((f32x4*)out)[sb + i] = v;
}

// ---------------------------------------------------------------------------
// workspace layout (bytes; ~203 MB)
// ---------------------------------------------------------------------------
#define OFF_WTQKV  ((size_t)0)           // bf16 [2304][768]
#define OFF_WTPROJ ((size_t)3538944)     // bf16 [768][768]
#define OFF_WTFC1  ((size_t)4718592)     // bf16 [3072][768]
#define OFF_WTFC2  ((size_t)9437184)     // bf16 [768][3072]
#define OFF_N1     ((size_t)14155776)    // bf16 [10240][768]; later ln1(ys)
#define OFF_BIG    ((size_t)29884416)    // bf16 qkv [10240][2304]; later h
#define OFF_OBUF   ((size_t)77070336)    // bf16 o [10240][768]
#define OFF_AOM    ((size_t)92798976)    // bf16 partial pairs (proj, then fc2)
#define OFF_A12    ((size_t)124256256)   // bf16 [10240][768]: a1, later a2
#define OFF_YS     ((size_t)155713536)   // f32 [10240][768]
#define OFF_L2Y    ((size_t)187170816)   // bf16 [10240][768]

extern "C" void kernel_launch(void* const* d_in, const int* in_sizes, int n_in,
                              void* d_out, int out_size, void* d_ws,
                              size_t ws_size, hipStream_t stream) {
  const float* x0 = (const float*)d_in[0];
  const float* x1 = (const float*)d_in[1];
  const float* x2 = (const float*)d_in[2];
  const float* x3 = (const float*)d_in[3];
  const float* x4 = (const float*)d_in[4];
  const float* ln1_g = (const float*)d_in[5];
  const float* ln1_b = (const float*)d_in[6];
  const float* ln2_g = (const float*)d_in[7];
  const float* ln2_b = (const float*)d_in[8];
  const float* qkv_w = (const float*)d_in[9];
  const float* qkv_b = (const float*)d_in[10];
  const float* proj_w = (const float*)d_in[11];
  const float* proj_b = (const float*)d_in[12];
  const float* fc1_w = (const float*)d_in[13];
  const float* fc1_b = (const float*)d_in[14];
  const float* fc2_w = (const float*)d_in[15];
  const float* fc2_b = (const float*)d_in[16];
  const float* at_dw = (const float*)d_in[17];
  const float* at_db = (const float*)d_in[18];
  const float* at_mw = (const float*)d_in[19];
  const float* at_mb = (const float*)d_in[20];
  const float* at_uw = (const float*)d_in[21];
  const float* at_ub = (const float*)d_in[22];
  const float* a2_dw = (const float*)d_in[23];
  const float* a2_db = (const float*)d_in[24];
  const float* a2_mw = (const float*)d_in[25];
  const float* a2_mb = (const float*)d_in[26];
  const float* a2_uw = (const float*)d_in[27];
  const float* a2_ub = (const float*)d_in[28];

  char* ws = (char*)d_ws;
  bf16* wt_qkv = (bf16*)(ws + OFF_WTQKV);
  bf16* wt_proj = (bf16*)(ws + OFF_WTPROJ);
  bf16* wt_fc1 = (bf16*)(ws + OFF_WTFC1);
  bf16* wt_fc2 = (bf16*)(ws + OFF_WTFC2);
  bf16* n1 = (bf16*)(ws + OFF_N1);
  bf16* qkvb = (bf16*)(ws + OFF_BIG);
  bf16* obuf = (bf16*)(ws + OFF_OBUF);
  bf16* mbuf = (bf16*)(ws + OFF_AOM);  // split-K bf16 partial pair
  bf16* a12 = (bf16*)(ws + OFF_A12);
  float* ysb = (float*)(ws + OFF_YS);
  bf16* l2y = (bf16*)(ws + OFF_L2Y);

  const dim3 b256(256);
  const dim3 b512(512);

  // 1. weight convert+transpose -> bf16 [N][K]
  transpose_to_bf16<<<dim3(72, 24), b256, 0, stream>>>(qkv_w, wt_qkv, 768, 2304);
  transpose_to_bf16<<<dim3(24, 24), b256, 0, stream>>>(proj_w, wt_proj, 768, 768);
  transpose_to_bf16<<<dim3(96, 24), b256, 0, stream>>>(fc1_w, wt_fc1, 768, 3072);
  transpose_to_bf16<<<dim3(24, 96), b256, 0, stream>>>(fc2_w, wt_fc2, 3072, 768);

  // 2. n1 = LN(xs)  (bf16)
  ln5_kernel<<<2560, b256, 0, stream>>>(x0, x1, x2, x3, x4, ln1_g, ln1_b, n1);

  // 3. qkv = n1 @ qkv_w + qkv_b  (bf16)   grid 40*9=360
  gemm256<1><<<360, b512, 0, stream>>>(n1, wt_qkv, qkv_b, qkvb, NQKV, 768, 768,
                                       9, 360, 0);

  // 4. a1 = adapter(n1)  (bf16)
  adapter_kernel<<<2560, b256, 0, stream>>>(n1, at_dw, at_db, at_mw, at_mb,
                                            at_uw, at_ub, a12);

  // 5. attention -> o (bf16)
  attn_v2<<<960, b256, 0, stream>>>(qkvb, obuf);

  // 6. ao = o @ proj_w + proj_b  — split-K=2, bf16 partials (grid 240)
  gemm256<1><<<240, b512, 0, stream>>>(obuf, wt_proj, proj_b, mbuf, CD, 384,
                                       768, 3, 120, (size_t)TOK * CD);

  // 7+8. ys = xs + (ao0+ao1) + cross(a1); ln1(ys)->n1, ln2(ys)->l2y
  fuse_res_ln<<<2560, b256, 0, stream>>>(x0, x1, x2, x3, x4, mbuf, a12, ysb,
                                         ln1_g, ln1_b, ln2_g, ln2_b, n1, l2y);

  // 9. a2 = adapter(ln1(ys))  (bf16, overwrites a1)
  adapter_kernel<<<2560, b256, 0, stream>>>(n1, a2_dw, a2_db, a2_mw, a2_mb,
                                            a2_uw, a2_ub, a12);

  // 10. h = gelu(ln2(ys) @ fc1_w + fc1_b)  (bf16)  grid 40*12=480
  gemm256<2><<<480, b512, 0, stream>>>(l2y, wt_fc1, fc1_b, qkvb, NHID, 768,
                                       768, 12, 480, 0);

  // 11. m = h @ fc2_w + fc2_b  — split-K=2, bf16 partials (grid 240)
  gemm256<1><<<240, b512, 0, stream>>>(qkvb, wt_fc2, fc2_b, mbuf, CD, 1536,
                                       3072, 3, 120, (size_t)TOK * CD);

  // 12. z = ys + (m0+m1) + cross(a2) -> d_out
  cross_residual<<<dim3(1536, 5), b256, 0, stream>>>(ysb, mbuf, a12,
                                                     (float*)d_out);
}

// Round 10
// 375.469 us; speedup vs baseline: 1.1607x; 1.1418x over previous
//
#include <hip/hip_runtime.h>
#include <math.h>

// ---------------------------------------------------------------------------
// Shapes: 5 streams x B=2 x N=1024 x C=768; H=12 heads x D=64; AD=8; HID=3072
// TOK = 5*2*1024 = 10240 rows everywhere.
// ---------------------------------------------------------------------------
typedef __bf16 bf16;
typedef __attribute__((ext_vector_type(8))) __bf16 bf16x8;
typedef __attribute__((ext_vector_type(4))) __bf16 bf16x4;
typedef __attribute__((ext_vector_type(4))) float f32x4;
typedef __attribute__((ext_vector_type(16))) float f32x16;

#define TOK   10240
#define CD    768
#define NQKV  2304
#define NHID  3072
#define SEQ   1024
#define NH    12

__device__ __forceinline__ f32x4 mfma16(bf16x8 a, bf16x8 b, f32x4 c) {
  return __builtin_amdgcn_mfma_f32_16x16x32_bf16(a, b, c, 0, 0, 0);
}
__device__ __forceinline__ f32x16 mfma32(bf16x8 a, bf16x8 b, f32x16 c) {
  return __builtin_amdgcn_mfma_f32_32x32x16_bf16(a, b, c, 0, 0, 0);
}

// async global->LDS, 16B per lane. LDS dest must be wave-uniform base;
// HW writes at base + lane*16. Global src is per-lane.
__device__ __forceinline__ void gload16(const void* g, void* l) {
  __builtin_amdgcn_global_load_lds(
      (const __attribute__((address_space(1))) void*)g,
      (__attribute__((address_space(3))) void*)l, 16, 0, 0);
}

__device__ __forceinline__ unsigned pack2(bf16 a, bf16 b) {
  union { unsigned short u[2]; unsigned v; } x;
  x.u[0] = __builtin_bit_cast(unsigned short, a);
  x.u[1] = __builtin_bit_cast(unsigned short, b);
  return x.v;
}

__device__ __forceinline__ f32x4 b4tof(const bf16* p) {
  bf16x4 v = *(const bf16x4*)p;
  f32x4 r;
#pragma unroll
  for (int j = 0; j < 4; ++j) r[j] = (float)v[j];
  return r;
}

// tanh-approx GELU (abs err ~3e-3, fine vs 0.11 threshold); __expf is HW exp
__device__ __forceinline__ float fast_gelu(float v) {
  float u = 0.7978845608f * (v + 0.044715f * v * v * v);
  float e = __expf(fminf(2.f * u, 30.f));
  return 0.5f * v * (1.f + (e - 1.f) / (e + 1.f));
}

// ---------------------------------------------------------------------------
// Weight convert+transpose: in [K][N] f32 -> out [N][K] bf16
// ---------------------------------------------------------------------------
__global__ __launch_bounds__(256) void transpose_to_bf16(
    const float* __restrict__ in, bf16* __restrict__ out, int K, int N) {
  __shared__ float tile[32][33];
  const int bn = blockIdx.x * 32, bk = blockIdx.y * 32;
  const int r = threadIdx.x >> 5, c = threadIdx.x & 31;
#pragma unroll
  for (int i = 0; i < 4; ++i)
    tile[r + 8 * i][c] = in[(size_t)(bk + r + 8 * i) * N + bn + c];
  __syncthreads();
#pragma unroll
  for (int i = 0; i < 4; ++i)
    out[(size_t)(bn + r + 8 * i) * K + bk + c] = (bf16)tile[c][r + 8 * i];
}

// ---------------------------------------------------------------------------
// LN over 5 stacked stream inputs -> bf16 [TOK][768]
// ---------------------------------------------------------------------------
__global__ __launch_bounds__(256) void ln5_kernel(
    const float* __restrict__ x0, const float* __restrict__ x1,
    const float* __restrict__ x2, const float* __restrict__ x3,
    const float* __restrict__ x4, const float* __restrict__ g,
    const float* __restrict__ b, bf16* __restrict__ out) {
  const int w = threadIdx.x >> 6, lane = threadIdx.x & 63;
  const int row = blockIdx.x * 4 + w;
  const int s = row >> 11, rem = row & 2047;
  const float* xp;
  switch (s) {
    case 0: xp = x0; break; case 1: xp = x1; break; case 2: xp = x2; break;
    case 3: xp = x3; break; default: xp = x4; break;
  }
  const f32x4* xr = (const f32x4*)(xp + (size_t)rem * CD);
  f32x4 v[3];
#pragma unroll
  for (int i = 0; i < 3; ++i) v[i] = xr[lane + 64 * i];
  float sum = 0.f;
#pragma unroll
  for (int i = 0; i < 3; ++i)
#pragma unroll
    for (int j = 0; j < 4; ++j) sum += v[i][j];
#pragma unroll
  for (int m = 32; m >= 1; m >>= 1) sum += __shfl_xor(sum, m);
  const float mu = sum * (1.f / 768.f);
  float vs = 0.f;
#pragma unroll
  for (int i = 0; i < 3; ++i)
#pragma unroll
    for (int j = 0; j < 4; ++j) { float d = v[i][j] - mu; vs += d * d; }
#pragma unroll
  for (int m = 32; m >= 1; m >>= 1) vs += __shfl_xor(vs, m);
  const float rstd = rsqrtf(vs * (1.f / 768.f) + 1e-5f);
  const f32x4* gp = (const f32x4*)g;
  const f32x4* bp = (const f32x4*)b;
  bf16* orow = out + (size_t)row * CD;
#pragma unroll
  for (int i = 0; i < 3; ++i) {
    const int c4 = lane + 64 * i;
    f32x4 gg = gp[c4], bb = bp[c4];
    bf16x4 o;
#pragma unroll
    for (int j = 0; j < 4; ++j)
      o[j] = (bf16)((v[i][j] - mu) * rstd * gg[j] + bb[j]);
    *(bf16x4*)(orow + c4 * 4) = o;
  }
}

// ---------------------------------------------------------------------------
// FUSED: ys = xs + ao(f32) + cross(a1 bf16); write ys (bf16) +
// ln1(ys),ln2(ys) (bf16). ys stored bf16 (saves 31 MB traffic; |ys|<~6 so
// quantization ~0.03 abs, well inside the 0.11 budget).
// ---------------------------------------------------------------------------
__global__ __launch_bounds__(256) void fuse_res_ln(
    const float* __restrict__ x0, const float* __restrict__ x1,
    const float* __restrict__ x2, const float* __restrict__ x3,
    const float* __restrict__ x4, const float* __restrict__ add,
    const bf16* __restrict__ a, bf16* __restrict__ ys,
    const float* __restrict__ g1, const float* __restrict__ b1,
    const float* __restrict__ g2, const float* __restrict__ b2,
    bf16* __restrict__ o1, bf16* __restrict__ o2) {
  const int w = threadIdx.x >> 6, lane = threadIdx.x & 63;
  const int row = blockIdx.x * 4 + w;
  const int s = row >> 11, rem = row & 2047;
  const float* xp;
  switch (s) {
    case 0: xp = x0; break; case 1: xp = x1; break; case 2: xp = x2; break;
    case 3: xp = x3; break; default: xp = x4; break;
  }
  const f32x4* xr = (const f32x4*)(xp + (size_t)rem * CD);
  const f32x4* ar = (const f32x4*)(add + (size_t)row * CD);
  const bf16* am = a + (size_t)(row - 2048) * CD;
  const bf16* ap = a + (size_t)(row + 2048) * CD;
  f32x4 v[3];
#pragma unroll
  for (int i = 0; i < 3; ++i) {
    const int c4 = lane + 64 * i;
    f32x4 t = xr[c4] + ar[c4];
    if (s > 0) t += b4tof(am + c4 * 4);
    if (s < 4) t += b4tof(ap + c4 * 4);
    v[i] = t;
  }
  bf16* yr = ys + (size_t)row * CD;
#pragma unroll
  for (int i = 0; i < 3; ++i) {
    const int c4 = lane + 64 * i;
    bf16x4 yo;
#pragma unroll
    for (int j = 0; j < 4; ++j) yo[j] = (bf16)v[i][j];
    *(bf16x4*)(yr + c4 * 4) = yo;
  }

  float sum = 0.f;
#pragma unroll
  for (int i = 0; i < 3; ++i)
#pragma unroll
    for (int j = 0; j < 4; ++j) sum += v[i][j];
#pragma unroll
  for (int m = 32; m >= 1; m >>= 1) sum += __shfl_xor(sum, m);
  const float mu = sum * (1.f / 768.f);
  float vs = 0.f;
#pragma unroll
  for (int i = 0; i < 3; ++i)
#pragma unroll
    for (int j = 0; j < 4; ++j) { float d = v[i][j] - mu; vs += d * d; }
#pragma unroll
  for (int m = 32; m >= 1; m >>= 1) vs += __shfl_xor(vs, m);
  const float rstd = rsqrtf(vs * (1.f / 768.f) + 1e-5f);
  bf16* r1 = o1 + (size_t)row * CD;
  bf16* r2 = o2 + (size_t)row * CD;
#pragma unroll
  for (int i = 0; i < 3; ++i) {
    const int c4 = lane + 64 * i;
    f32x4 gg1 = ((const f32x4*)g1)[c4], bb1 = ((const f32x4*)b1)[c4];
    f32x4 gg2 = ((const f32x4*)g2)[c4], bb2 = ((const f32x4*)b2)[c4];
    bf16x4 oa, ob;
#pragma unroll
    for (int j = 0; j < 4; ++j) {
      float n = (v[i][j] - mu) * rstd;
      oa[j] = (bf16)(n * gg1[j] + bb1[j]);
      ob[j] = (bf16)(n * gg2[j] + bb2[j]);
    }
    *(bf16x4*)(r1 + c4 * 4) = oa;
    *(bf16x4*)(r2 + c4 * 4) = ob;
  }
}

// ---------------------------------------------------------------------------
// GEMM 256x256, BK=64, 8 waves (2M x 4N), 8-phase schedule (T2+T3+T4+T5).
// EXACT revert to the proven-best R5 configuration (fc1 = 88 us measured).
// C[M,N] = A[M, ldk restricted to Klen window] @ Bt[N, same]^T + bias.
// Optional split-K: grid = nkp * nbm * nbn; kp = wg / bpk selects the K-part
// (A,Bt offset kp*Klen; output offset kp*kpstride elements; bias only kp==0).
// LDS double-buffered, k-chunk (16B) XOR-swizzled by (row&7) on BOTH global
// source (pre-swizzle) and ds_read. Counted vmcnt(4) at phases 4 and 8 only.
// EPI: 0 = f32 store, 1 = bf16 store, 2 = fast-GELU -> bf16 store
// ---------------------------------------------------------------------------
#define GBAR() __builtin_amdgcn_s_barrier()

#define LOADA(MH, BUF)                                                      \
  _Pragma("unroll") for (int m_ = 0; m_ < 4; ++m_) {                        \
    af[m_][0] =                                                             \
        *(const bf16x8*)&As[BUF][((MH)*128 + arow + m_ * 16) * 64 + ach0];  \
    af[m_][1] =                                                             \
        *(const bf16x8*)&As[BUF][((MH)*128 + arow + m_ * 16) * 64 + ach1];  \
  }

#define LOADB(DST, NH, BUF)                                                 \
  _Pragma("unroll") for (int n_ = 0; n_ < 2; ++n_) {                        \
    DST[n_][0] =                                                            \
        *(const bf16x8*)&Bs[BUF][(brow + (NH)*32 + n_ * 16) * 64 + ach0];   \
    DST[n_][1] =                                                            \
        *(const bf16x8*)&Bs[BUF][(brow + (NH)*32 + n_ * 16) * 64 + ach1];   \
  }

#define MFMA_PH(MH, NH, BF)                                                 \
  __builtin_amdgcn_s_setprio(1);                                            \
  _Pragma("unroll") for (int m_ = 0; m_ < 4; ++m_)                          \
  _Pragma("unroll") for (int n_ = 0; n_ < 2; ++n_) {                        \
    acc[(MH)*4 + m_][(NH)*2 + n_] =                                         \
        mfma16(af[m_][0], BF[n_][0], acc[(MH)*4 + m_][(NH)*2 + n_]);        \
    acc[(MH)*4 + m_][(NH)*2 + n_] =                                         \
        mfma16(af[m_][1], BF[n_][1], acc[(MH)*4 + m_][(NH)*2 + n_]);        \
  }                                                                         \
  __builtin_amdgcn_s_setprio(0);

template <int EPI>
__global__ __launch_bounds__(512, 2) void gemm256(
    const bf16* __restrict__ A, const bf16* __restrict__ Bt,
    const float* __restrict__ bias, void* __restrict__ Cout, int N, int Klen,
    int ldk, int nbn, int bpk, size_t kpstride) {
  __shared__ bf16 As[2][16384];
  __shared__ bf16 Bs[2][16384];
  const int t = threadIdx.x, lane = t & 63, w = t >> 6;
  const int wm = w >> 2, wn = w & 3;

  // bijective XCD-chunked remap (gridDim.x % 8 == 0 by construction)
  const int chunkg = gridDim.x >> 3;
  const int wg = (blockIdx.x & 7) * chunkg + (blockIdx.x >> 3);
  const int kp = wg / bpk, rem = wg % bpk;
  const int bm = rem / nbn, bn = rem % nbn;

  f32x4 acc[8][4] = {};

  const int srow = t >> 3;
  const int scol = ((t & 7) ^ (srow & 7)) << 3;
  const size_t koff = (size_t)kp * Klen;
  const bf16* Ab = A + (size_t)(bm * 256 + srow) * ldk + koff + scol;
  const bf16* Bb = Bt + (size_t)(bn * 256 + srow) * ldk + koff + scol;
  const size_t r64 = (size_t)64 * ldk;

  auto stage_a = [&](int buf, int h, int kt) {
    const bf16* g = Ab + (size_t)h * 128 * ldk + (size_t)kt * 64;
    gload16(g, &As[buf][h * 8192 + w * 512]);
    gload16(g + r64, &As[buf][h * 8192 + 4096 + w * 512]);
  };
  auto stage_b = [&](int buf, int h, int kt) {
    const bf16* g = Bb + (size_t)h * 128 * ldk + (size_t)kt * 64;
    gload16(g, &Bs[buf][h * 8192 + w * 512]);
    gload16(g + r64, &Bs[buf][h * 8192 + 4096 + w * 512]);
  };

  const int arow = wm * 64 + (lane & 15);
  const int brow = wn * 64 + (lane & 15);
  const int ach0 = (((lane >> 4) + 0) ^ (lane & 7)) << 3;
  const int ach1 = (((lane >> 4) + 4) ^ (lane & 7)) << 3;

  // prologue: T0 {A0,B0,B1,A1}, T1 {A0,B0}
  stage_a(0, 0, 0); stage_b(0, 0, 0); stage_b(0, 1, 0); stage_a(0, 1, 0);
  stage_a(1, 0, 1); stage_b(1, 0, 1);
  asm volatile("s_waitcnt vmcnt(4)" ::: "memory");  // T0 landed
  GBAR();

  const int NT = Klen >> 6, NI = NT >> 1;
  bf16x8 af[4][2], bf0[2][2], bf1[2][2];

  for (int j = 0; j < NI; ++j) {
    const int tA = 2 * j, tB = 2 * j + 1;
    const bool notlast = (j + 1 < NI);

    // ======== tile tA from buf 0 ========
    LOADA(0, 0);
    LOADB(bf0, 0, 0);
    stage_b(1, 1, tB);
    GBAR();
    MFMA_PH(0, 0, bf0);
    GBAR();
    LOADB(bf1, 1, 0);
    stage_a(1, 1, tB);
    GBAR();
    MFMA_PH(0, 1, bf1);
    GBAR();
    LOADA(1, 0);
    if (notlast) stage_a(0, 0, tA + 2);
    GBAR();
    MFMA_PH(1, 0, bf0);
    GBAR();
    if (notlast) {
      stage_b(0, 0, tA + 2);
      asm volatile("s_waitcnt vmcnt(4)" ::: "memory");
    } else {
      asm volatile("s_waitcnt vmcnt(0)" ::: "memory");
    }
    GBAR();
    MFMA_PH(1, 1, bf1);
    GBAR();

    // ======== tile tB from buf 1 ========
    LOADA(0, 1);
    LOADB(bf0, 0, 1);
    if (notlast) stage_b(0, 1, tA + 2);
    GBAR();
    MFMA_PH(0, 0, bf0);
    GBAR();
    LOADB(bf1, 1, 1);
    if (notlast) stage_a(0, 1, tA + 2);
    GBAR();
    MFMA_PH(0, 1, bf1);
    GBAR();
    LOADA(1, 1);
    if (notlast) stage_a(1, 0, tB + 2);
    GBAR();
    MFMA_PH(1, 0, bf0);
    GBAR();
    if (notlast) {
      stage_b(1, 0, tB + 2);
      asm volatile("s_waitcnt vmcnt(4)" ::: "memory");
    }
    GBAR();
    MFMA_PH(1, 1, bf1);
    GBAR();
  }

  // epilogue (bias only on kp==0 so split-K partials sum correctly)
#pragma unroll
  for (int am = 0; am < 8; ++am) {
    const int grow0 =
        bm * 256 + (am >> 2) * 128 + wm * 64 + (am & 3) * 16 + (lane >> 4) * 4;
#pragma unroll
    for (int an = 0; an < 4; ++an) {
      const int gcol = bn * 256 + wn * 64 + an * 16 + (lane & 15);
      const float bv = (kp == 0) ? bias[gcol] : 0.f;
#pragma unroll
      for (int r = 0; r < 4; ++r) {
        float v = acc[am][an][r] + bv;
        if (EPI == 2) v = fast_gelu(v);
        const size_t idx = (size_t)(grow0 + r) * N + gcol + kp * kpstride;
        if (EPI == 0) ((float*)Cout)[idx] = v;
        else ((bf16*)Cout)[idx] = (bf16)v;
      }
    }
  }
}

// ---------------------------------------------------------------------------
// Flash attention v2 — swapped-operand 32x32 MFMA, in-register softmax.
// launch_bounds(256,4): 4 blocks/CU (LDS 4x32KB=128K, VGPR 76 fits) ->
// all 960 blocks co-resident in one dispatch round.
// ---------------------------------------------------------------------------
__global__ __launch_bounds__(256, 4) void attn_v2(
    const bf16* __restrict__ qkv, bf16* __restrict__ obuf) {
  __shared__ bf16 Ks[2][4096];
  __shared__ bf16 Vt[2][4096];
  const int t = threadIdx.x, lane = t & 63, w = t >> 6;
  const int g = lane >> 5, q32 = lane & 31, rq7 = q32 & 7;

  const int xcd = blockIdx.x & 7, slot = blockIdx.x >> 3;
  const int work = xcd * 120 + slot;
  const int sbh = work >> 3, qt = work & 7;
  const int sb = sbh / NH, h = sbh % NH;
  const size_t tokbase = (size_t)sb * SEQ;
  const int qoff = h * 64, koff = CD + h * 64, voff = 2 * CD + h * 64;

  const int qrow = qt * 128 + w * 32 + q32;
  bf16x8 qf[4];
  {
    const bf16* qp = qkv + (tokbase + qrow) * NQKV + qoff + g * 8;
#pragma unroll
    for (int kd = 0; kd < 4; ++kd) {
      bf16x8 v = *(const bf16x8*)(qp + kd * 16);
#pragma unroll
      for (int j = 0; j < 8; ++j) v[j] = (bf16)((float)v[j] * 0.125f);
      qf[kd] = v;
    }
  }

  const int skv1 = t >> 3, sc1 = (t & 7) ^ (skv1 & 7);
  const int skv2 = (t + 256) >> 3, sc2 = (t & 7) ^ (skv2 & 7);
  const int vkv0 = 2 * (t & 31);
  const int vd0 = 8 * (t >> 5);
  const int c0 = (vkv0 & 51) | ((vkv0 & 4) << 1) | ((vkv0 & 8) >> 1);
  const int vchunk = c0 >> 3, vsub = c0 & 7;
  const bf16* kbase = qkv + tokbase * NQKV + koff;
  const bf16* vbase = qkv + tokbase * NQKV + voff;

  {
    const bf16* kb0 = kbase;
    gload16(kb0 + (size_t)skv1 * NQKV + sc1 * 8, &Ks[0][w * 512]);
    gload16(kb0 + (size_t)skv2 * NQKV + sc2 * 8, &Ks[0][2048 + w * 512]);
    const bf16* vp = vbase + (size_t)vkv0 * NQKV + vd0;
    bf16x8 r0 = *(const bf16x8*)vp;
    bf16x8 r1 = *(const bf16x8*)(vp + NQKV);
#pragma unroll
    for (int j = 0; j < 8; ++j) {
      const int d = vd0 + j;
      *(unsigned*)&Vt[0][d * 64 + ((vchunk ^ j) << 3) + vsub] =
          pack2(r0[j], r1[j]);
    }
  }
  __syncthreads();

  float m_run = -1e30f, l_run = 0.f;
  f32x16 oT0 = {}, oT1 = {};
  int cur = 0;

  for (int kt = 0; kt < 16; ++kt) {
    bf16x8 nv0, nv1;
    if (kt < 15) {
      const bf16* vp = vbase + (size_t)((kt + 1) * 64 + vkv0) * NQKV + vd0;
      nv0 = *(const bf16x8*)vp;
      nv1 = *(const bf16x8*)(vp + NQKV);
      const bf16* kb0 = kbase + (size_t)(kt + 1) * 64 * NQKV;
      gload16(kb0 + (size_t)skv1 * NQKV + sc1 * 8, &Ks[cur ^ 1][w * 512]);
      gload16(kb0 + (size_t)skv2 * NQKV + sc2 * 8,
              &Ks[cur ^ 1][2048 + w * 512]);
    }

    f32x16 sT0 = {}, sT1 = {};
#pragma unroll
    for (int kd = 0; kd < 4; ++kd) {
      bf16x8 kf0 =
          *(const bf16x8*)&Ks[cur][q32 * 64 + (((2 * kd + g) ^ rq7) << 3)];
      bf16x8 kf1 = *(const bf16x8*)&Ks[cur][(32 + q32) * 64 +
                                            (((2 * kd + g) ^ rq7) << 3)];
      sT0 = mfma32(kf0, qf[kd], sT0);
      sT1 = mfma32(kf1, qf[kd], sT1);
    }

    float mt = sT0[0];
#pragma unroll
    for (int r = 1; r < 16; ++r) mt = fmaxf(mt, sT0[r]);
#pragma unroll
    for (int r = 0; r < 16; ++r) mt = fmaxf(mt, sT1[r]);
    mt = fmaxf(mt, __shfl_xor(mt, 32));
    const float mnew = fmaxf(m_run, mt);
    const float alpha = __expf(m_run - mnew);
    m_run = mnew;
    float rs = 0.f;
#pragma unroll
    for (int r = 0; r < 16; ++r) {
      sT0[r] = __expf(sT0[r] - mnew);
      rs += sT0[r];
    }
#pragma unroll
    for (int r = 0; r < 16; ++r) {
      sT1[r] = __expf(sT1[r] - mnew);
      rs += sT1[r];
    }
    rs += __shfl_xor(rs, 32);
    l_run = l_run * alpha + rs;
#pragma unroll
    for (int r = 0; r < 16; ++r) { oT0[r] *= alpha; oT1[r] *= alpha; }

    bf16x8 pa[4];
#pragma unroll
    for (int hh = 0; hh < 2; ++hh)
#pragma unroll
      for (int j = 0; j < 8; ++j) {
        pa[hh][j] = (bf16)sT0[8 * hh + j];
        pa[2 + hh][j] = (bf16)sT1[8 * hh + j];
      }

#pragma unroll
    for (int ks = 0; ks < 4; ++ks) {
      bf16x8 vf0 =
          *(const bf16x8*)&Vt[cur][q32 * 64 + (((2 * ks + g) ^ rq7) << 3)];
      bf16x8 vf1 = *(const bf16x8*)&Vt[cur][(32 + q32) * 64 +
                                            (((2 * ks + g) ^ rq7) << 3)];
      oT0 = mfma32(vf0, pa[ks], oT0);
      oT1 = mfma32(vf1, pa[ks], oT1);
    }

    if (kt < 15) {
#pragma unroll
      for (int j = 0; j < 8; ++j) {
        const int d = vd0 + j;
        *(unsigned*)&Vt[cur ^ 1][d * 64 + ((vchunk ^ j) << 3) + vsub] =
            pack2(nv0[j], nv1[j]);
      }
    }
    __syncthreads();
    cur ^= 1;
  }

  const float rl = 1.f / l_run;
  bf16* orow = obuf + (tokbase + qrow) * CD + h * 64;
#pragma unroll
  for (int m = 0; m < 4; ++m) {
    bf16x4 o0, o1;
#pragma unroll
    for (int r = 0; r < 4; ++r) {
      o0[r] = (bf16)(oT0[4 * m + r] * rl);
      o1[r] = (bf16)(oT1[4 * m + r] * rl);
    }
    *(bf16x4*)(orow + 8 * m + 4 * g) = o0;
    *(bf16x4*)(orow + 32 + 8 * m + 4 * g) = o1;
  }
}

// ---------------------------------------------------------------------------
// Adapter: out = ((X@dw+db)@mw+mb)@uw+ub ; X bf16 [TOK][768], out bf16.
// ---------------------------------------------------------------------------
__global__ __launch_bounds__(256) void adapter_kernel(
    const bf16* __restrict__ X, const float* __restrict__ dw,
    const float* __restrict__ db, const float* __restrict__ mw,
    const float* __restrict__ mb, const float* __restrict__ uw,
    const float* __restrict__ ub, bf16* __restrict__ out) {
  const int tok = blockIdx.x * 4 + (threadIdx.x >> 6);
  const int lane = threadIdx.x & 63;
  const bf16* xr = X + (size_t)tok * CD;
  float xv[12];
#pragma unroll
  for (int i = 0; i < 12; ++i) xv[i] = (float)xr[lane + 64 * i];
  float h1[8] = {0, 0, 0, 0, 0, 0, 0, 0};
#pragma unroll
  for (int i = 0; i < 12; ++i) {
    const f32x4* dr = (const f32x4*)(dw + (size_t)(lane + 64 * i) * 8);
    f32x4 d0 = dr[0], d1 = dr[1];
#pragma unroll
    for (int j = 0; j < 4; ++j) {
      h1[j] += xv[i] * d0[j];
      h1[4 + j] += xv[i] * d1[j];
    }
  }
#pragma unroll
  for (int m = 1; m < 64; m <<= 1)
#pragma unroll
    for (int j = 0; j < 8; ++j) h1[j] += __shfl_xor(h1[j], m);
#pragma unroll
  for (int j = 0; j < 8; ++j) h1[j] += db[j];
  float h2[8];
#pragma unroll
  for (int k = 0; k < 8; ++k) {
    float v = mb[k];
#pragma unroll
    for (int j = 0; j < 8; ++j) v += h1[j] * mw[j * 8 + k];
    h2[k] = v;
  }
#pragma unroll
  for (int i = 0; i < 12; ++i) {
    const int c = lane + 64 * i;
    float v = ub[c];
#pragma unroll
    for (int k = 0; k < 8; ++k) v += h2[k] * uw[k * CD + c];
    out[(size_t)tok * CD + c] = (bf16)v;
  }
}

// ---------------------------------------------------------------------------
// Final: z[s] = ys[s](bf16) + m0[s] + m1[s] + cross(a2)   (out f32)
// ---------------------------------------------------------------------------
__global__ __launch_bounds__(256) void cross_residual(
    const bf16* __restrict__ ys, const bf16* __restrict__ m01,
    const bf16* __restrict__ a, float* __restrict__ out) {
  const int s = blockIdx.y;
  const size_t i = (size_t)blockIdx.x * 256 + threadIdx.x;  // group-of-4 index
  const size_t spitch = (size_t)2048 * 768 / 4;
  const size_t sb = (size_t)s * spitch;
  const size_t mstride = (size_t)TOK * CD / 4;
  f32x4 v = b4tof(ys + (sb + i) * 4);
  v += b4tof(m01 + (sb + i) * 4);
  v += b4tof(m01 + (mstride + sb + i) * 4);
  if (s > 0) v += b4tof(a + (sb - spitch + i) * 4);
  if (s < 4) v += b4tof(a + (sb + spitch + i) * 4);
  ((f32x4*)out)[sb + i] = v;
}

// ---------------------------------------------------------------------------
// workspace layout (bytes; ~203 MB)
// ---------------------------------------------------------------------------
#define OFF_WTQKV  ((size_t)0)           // bf16 [2304][768]
#define OFF_WTPROJ ((size_t)3538944)     // bf16 [768][768]
#define OFF_WTFC1  ((size_t)4718592)     // bf16 [3072][768]
#define OFF_WTFC2  ((size_t)9437184)     // bf16 [768][3072]
#define OFF_N1     ((size_t)14155776)    // bf16 [10240][768]; later ln1(ys)
#define OFF_BIG    ((size_t)29884416)    // bf16 qkv [10240][2304]; later h
#define OFF_OBUF   ((size_t)77070336)    // bf16 o [10240][768]
#define OFF_AOM    ((size_t)92798976)    // f32 ao; later bf16 m0,m1 stacked
#define OFF_A12    ((size_t)124256256)   // bf16 [10240][768]: a1, later a2
#define OFF_YS     ((size_t)155713536)   // bf16 [10240][768] ys
#define OFF_L2Y    ((size_t)187170816)   // bf16 [10240][768]

extern "C" void kernel_launch(void* const* d_in, const int* in_sizes, int n_in,
                              void* d_out, int out_size, void* d_ws,
                              size_t ws_size, hipStream_t stream) {
  const float* x0 = (const float*)d_in[0];
  const float* x1 = (const float*)d_in[1];
  const float* x2 = (const float*)d_in[2];
  const float* x3 = (const float*)d_in[3];
  const float* x4 = (const float*)d_in[4];
  const float* ln1_g = (const float*)d_in[5];
  const float* ln1_b = (const float*)d_in[6];
  const float* ln2_g = (const float*)d_in[7];
  const float* ln2_b = (const float*)d_in[8];
  const float* qkv_w = (const float*)d_in[9];
  const float* qkv_b = (const float*)d_in[10];
  const float* proj_w = (const float*)d_in[11];
  const float* proj_b = (const float*)d_in[12];
  const float* fc1_w = (const float*)d_in[13];
  const float* fc1_b = (const float*)d_in[14];
  const float* fc2_w = (const float*)d_in[15];
  const float* fc2_b = (const float*)d_in[16];
  const float* at_dw = (const float*)d_in[17];
  const float* at_db = (const float*)d_in[18];
  const float* at_mw = (const float*)d_in[19];
  const float* at_mb = (const float*)d_in[20];
  const float* at_uw = (const float*)d_in[21];
  const float* at_ub = (const float*)d_in[22];
  const float* a2_dw = (const float*)d_in[23];
  const float* a2_db = (const float*)d_in[24];
  const float* a2_mw = (const float*)d_in[25];
  const float* a2_mb = (const float*)d_in[26];
  const float* a2_uw = (const float*)d_in[27];
  const float* a2_ub = (const float*)d_in[28];

  char* ws = (char*)d_ws;
  bf16* wt_qkv = (bf16*)(ws + OFF_WTQKV);
  bf16* wt_proj = (bf16*)(ws + OFF_WTPROJ);
  bf16* wt_fc1 = (bf16*)(ws + OFF_WTFC1);
  bf16* wt_fc2 = (bf16*)(ws + OFF_WTFC2);
  bf16* n1 = (bf16*)(ws + OFF_N1);
  bf16* qkvb = (bf16*)(ws + OFF_BIG);
  bf16* obuf = (bf16*)(ws + OFF_OBUF);
  float* aof = (float*)(ws + OFF_AOM);   // proj out (f32)
  bf16* mbuf = (bf16*)(ws + OFF_AOM);    // fc2 split partials m0,m1 (bf16 x2)
  bf16* a12 = (bf16*)(ws + OFF_A12);
  bf16* ysb = (bf16*)(ws + OFF_YS);
  bf16* l2y = (bf16*)(ws + OFF_L2Y);

  const dim3 b256(256);
  const dim3 b512(512);

  // 1. weight convert+transpose -> bf16 [N][K]
  transpose_to_bf16<<<dim3(72, 24), b256, 0, stream>>>(qkv_w, wt_qkv, 768, 2304);
  transpose_to_bf16<<<dim3(24, 24), b256, 0, stream>>>(proj_w, wt_proj, 768, 768);
  transpose_to_bf16<<<dim3(96, 24), b256, 0, stream>>>(fc1_w, wt_fc1, 768, 3072);
  transpose_to_bf16<<<dim3(24, 96), b256, 0, stream>>>(fc2_w, wt_fc2, 3072, 768);

  // 2. n1 = LN(xs)  (bf16)
  ln5_kernel<<<2560, b256, 0, stream>>>(x0, x1, x2, x3, x4, ln1_g, ln1_b, n1);

  // 3. qkv = n1 @ qkv_w + qkv_b  (bf16)   grid 40*9=360
  gemm256<1><<<360, b512, 0, stream>>>(n1, wt_qkv, qkv_b, qkvb, NQKV, 768, 768,
                                       9, 360, 0);

  // 4. a1 = adapter(n1)  (bf16)
  adapter_kernel<<<2560, b256, 0, stream>>>(n1, at_dw, at_db, at_mw, at_mb,
                                            at_uw, at_ub, a12);

  // 5. attention -> o (bf16)
  attn_v2<<<960, b256, 0, stream>>>(qkvb, obuf);

  // 6. ao = o @ proj_w + proj_b  (f32)   grid 40*3=120
  gemm256<0><<<120, b512, 0, stream>>>(obuf, wt_proj, proj_b, aof, CD, 768,
                                       768, 3, 120, 0);

  // 7+8. ys = xs + ao + cross(a1) (bf16); ln1(ys)->n1, ln2(ys)->l2y
  fuse_res_ln<<<2560, b256, 0, stream>>>(x0, x1, x2, x3, x4, aof, a12, ysb,
                                         ln1_g, ln1_b, ln2_g, ln2_b, n1, l2y);

  // 9. a2 = adapter(ln1(ys))  (bf16, overwrites a1)
  adapter_kernel<<<2560, b256, 0, stream>>>(n1, a2_dw, a2_db, a2_mw, a2_mb,
                                            a2_uw, a2_ub, a12);

  // 10. h = gelu(ln2(ys) @ fc1_w + fc1_b)  (bf16)   grid 40*12=480
  gemm256<2><<<480, b512, 0, stream>>>(l2y, wt_fc1, fc1_b, qkvb, NHID, 768,
                                       768, 12, 480, 0);

  // 11. m = h @ fc2_w + fc2_b  — split-K=2, bf16 partials m0,m1
  gemm256<1><<<240, b512, 0, stream>>>(qkvb, wt_fc2, fc2_b, mbuf, CD, 1536,
                                       3072, 3, 120, (size_t)TOK * CD);

  // 12. z = ys + (m0+m1) + cross(a2) -> d_out
  cross_residual<<<dim3(1536, 5), b256, 0, stream>>>(ysb, mbuf, a12,
                                                     (float*)d_out);
}

// Round 11
// 362.199 us; speedup vs baseline: 1.2032x; 1.0366x over previous
//
#include <hip/hip_runtime.h>
#include <math.h>

// ---------------------------------------------------------------------------
// Shapes: 5 streams x B=2 x N=1024 x C=768; H=12 heads x D=64; AD=8; HID=3072
// TOK = 5*2*1024 = 10240 rows everywhere.
// ---------------------------------------------------------------------------
typedef __bf16 bf16;
typedef __attribute__((ext_vector_type(8))) __bf16 bf16x8;
typedef __attribute__((ext_vector_type(4))) __bf16 bf16x4;
typedef __attribute__((ext_vector_type(4))) float f32x4;
typedef __attribute__((ext_vector_type(16))) float f32x16;

#define TOK   10240
#define CD    768
#define NQKV  2304
#define NHID  3072
#define SEQ   1024
#define NH    12

__device__ __forceinline__ f32x4 mfma16(bf16x8 a, bf16x8 b, f32x4 c) {
  return __builtin_amdgcn_mfma_f32_16x16x32_bf16(a, b, c, 0, 0, 0);
}
__device__ __forceinline__ f32x16 mfma32(bf16x8 a, bf16x8 b, f32x16 c) {
  return __builtin_amdgcn_mfma_f32_32x32x16_bf16(a, b, c, 0, 0, 0);
}

// async global->LDS, 16B per lane. LDS dest must be wave-uniform base;
// HW writes at base + lane*16. Global src is per-lane.
__device__ __forceinline__ void gload16(const void* g, void* l) {
  __builtin_amdgcn_global_load_lds(
      (const __attribute__((address_space(1))) void*)g,
      (__attribute__((address_space(3))) void*)l, 16, 0, 0);
}

__device__ __forceinline__ unsigned pack2(bf16 a, bf16 b) {
  union { unsigned short u[2]; unsigned v; } x;
  x.u[0] = __builtin_bit_cast(unsigned short, a);
  x.u[1] = __builtin_bit_cast(unsigned short, b);
  return x.v;
}

__device__ __forceinline__ f32x4 b4tof(const bf16* p) {
  bf16x4 v = *(const bf16x4*)p;
  f32x4 r;
#pragma unroll
  for (int j = 0; j < 4; ++j) r[j] = (float)v[j];
  return r;
}

// tanh-approx GELU (abs err ~3e-3, fine vs 0.11 threshold); __expf is HW exp
__device__ __forceinline__ float fast_gelu(float v) {
  float u = 0.7978845608f * (v + 0.044715f * v * v * v);
  float e = __expf(fminf(2.f * u, 30.f));
  return 0.5f * v * (1.f + (e - 1.f) / (e + 1.f));
}

// ---------------------------------------------------------------------------
// Batched weight convert+transpose: all 4 weights in ONE launch.
// in [K][N] f32 -> out [N][K] bf16, 32x32 tiles.
// tile counts: qkv 72x24=1728, proj 24x24=576, fc1 96x24=2304, fc2 24x96=2304
// ---------------------------------------------------------------------------
__global__ __launch_bounds__(256) void transpose_all(
    const float* __restrict__ qkv_w, const float* __restrict__ proj_w,
    const float* __restrict__ fc1_w, const float* __restrict__ fc2_w,
    bf16* __restrict__ o_qkv, bf16* __restrict__ o_proj,
    bf16* __restrict__ o_fc1, bf16* __restrict__ o_fc2) {
  __shared__ float tile[32][33];
  int b = blockIdx.x;
  const float* in;
  bf16* out;
  int K, N, tx, ty;
  if (b < 1728) {
    in = qkv_w; out = o_qkv; K = 768; N = 2304; tx = b % 72; ty = b / 72;
  } else if (b < 2304) {
    b -= 1728;
    in = proj_w; out = o_proj; K = 768; N = 768; tx = b % 24; ty = b / 24;
  } else if (b < 4608) {
    b -= 2304;
    in = fc1_w; out = o_fc1; K = 768; N = 3072; tx = b % 96; ty = b / 96;
  } else {
    b -= 4608;
    in = fc2_w; out = o_fc2; K = 3072; N = 768; tx = b % 24; ty = b / 24;
  }
  const int bn = tx * 32, bk = ty * 32;
  const int r = threadIdx.x >> 5, c = threadIdx.x & 31;
#pragma unroll
  for (int i = 0; i < 4; ++i)
    tile[r + 8 * i][c] = in[(size_t)(bk + r + 8 * i) * N + bn + c];
  __syncthreads();
#pragma unroll
  for (int i = 0; i < 4; ++i)
    out[(size_t)(bn + r + 8 * i) * K + bk + c] = (bf16)tile[c][r + 8 * i];
}

// ---------------------------------------------------------------------------
// LN over 5 stacked stream inputs -> bf16 [TOK][768]
// ---------------------------------------------------------------------------
__global__ __launch_bounds__(256) void ln5_kernel(
    const float* __restrict__ x0, const float* __restrict__ x1,
    const float* __restrict__ x2, const float* __restrict__ x3,
    const float* __restrict__ x4, const float* __restrict__ g,
    const float* __restrict__ b, bf16* __restrict__ out) {
  const int w = threadIdx.x >> 6, lane = threadIdx.x & 63;
  const int row = blockIdx.x * 4 + w;
  const int s = row >> 11, rem = row & 2047;
  const float* xp;
  switch (s) {
    case 0: xp = x0; break; case 1: xp = x1; break; case 2: xp = x2; break;
    case 3: xp = x3; break; default: xp = x4; break;
  }
  const f32x4* xr = (const f32x4*)(xp + (size_t)rem * CD);
  f32x4 v[3];
#pragma unroll
  for (int i = 0; i < 3; ++i) v[i] = xr[lane + 64 * i];
  float sum = 0.f;
#pragma unroll
  for (int i = 0; i < 3; ++i)
#pragma unroll
    for (int j = 0; j < 4; ++j) sum += v[i][j];
#pragma unroll
  for (int m = 32; m >= 1; m >>= 1) sum += __shfl_xor(sum, m);
  const float mu = sum * (1.f / 768.f);
  float vs = 0.f;
#pragma unroll
  for (int i = 0; i < 3; ++i)
#pragma unroll
    for (int j = 0; j < 4; ++j) { float d = v[i][j] - mu; vs += d * d; }
#pragma unroll
  for (int m = 32; m >= 1; m >>= 1) vs += __shfl_xor(vs, m);
  const float rstd = rsqrtf(vs * (1.f / 768.f) + 1e-5f);
  const f32x4* gp = (const f32x4*)g;
  const f32x4* bp = (const f32x4*)b;
  bf16* orow = out + (size_t)row * CD;
#pragma unroll
  for (int i = 0; i < 3; ++i) {
    const int c4 = lane + 64 * i;
    f32x4 gg = gp[c4], bb = bp[c4];
    bf16x4 o;
#pragma unroll
    for (int j = 0; j < 4; ++j)
      o[j] = (bf16)((v[i][j] - mu) * rstd * gg[j] + bb[j]);
    *(bf16x4*)(orow + c4 * 4) = o;
  }
}

// ---------------------------------------------------------------------------
// FUSED: ys = xs + (ao0+ao1 bf16 split-K partials) + cross(a1 bf16);
// write ys (bf16) + ln1(ys),ln2(ys) (bf16).
// ---------------------------------------------------------------------------
__global__ __launch_bounds__(256) void fuse_res_ln(
    const float* __restrict__ x0, const float* __restrict__ x1,
    const float* __restrict__ x2, const float* __restrict__ x3,
    const float* __restrict__ x4, const bf16* __restrict__ m01,
    const bf16* __restrict__ a, bf16* __restrict__ ys,
    const float* __restrict__ g1, const float* __restrict__ b1,
    const float* __restrict__ g2, const float* __restrict__ b2,
    bf16* __restrict__ o1, bf16* __restrict__ o2) {
  const int w = threadIdx.x >> 6, lane = threadIdx.x & 63;
  const int row = blockIdx.x * 4 + w;
  const int s = row >> 11, rem = row & 2047;
  const float* xp;
  switch (s) {
    case 0: xp = x0; break; case 1: xp = x1; break; case 2: xp = x2; break;
    case 3: xp = x3; break; default: xp = x4; break;
  }
  const f32x4* xr = (const f32x4*)(xp + (size_t)rem * CD);
  const bf16* p0 = m01 + (size_t)row * CD;
  const bf16* p1 = m01 + (size_t)TOK * CD + (size_t)row * CD;
  const bf16* am = a + (size_t)(row - 2048) * CD;
  const bf16* ap = a + (size_t)(row + 2048) * CD;
  f32x4 v[3];
#pragma unroll
  for (int i = 0; i < 3; ++i) {
    const int c4 = lane + 64 * i;
    f32x4 t = xr[c4] + b4tof(p0 + c4 * 4) + b4tof(p1 + c4 * 4);
    if (s > 0) t += b4tof(am + c4 * 4);
    if (s < 4) t += b4tof(ap + c4 * 4);
    v[i] = t;
  }
  bf16* yr = ys + (size_t)row * CD;
#pragma unroll
  for (int i = 0; i < 3; ++i) {
    const int c4 = lane + 64 * i;
    bf16x4 yo;
#pragma unroll
    for (int j = 0; j < 4; ++j) yo[j] = (bf16)v[i][j];
    *(bf16x4*)(yr + c4 * 4) = yo;
  }

  float sum = 0.f;
#pragma unroll
  for (int i = 0; i < 3; ++i)
#pragma unroll
    for (int j = 0; j < 4; ++j) sum += v[i][j];
#pragma unroll
  for (int m = 32; m >= 1; m >>= 1) sum += __shfl_xor(sum, m);
  const float mu = sum * (1.f / 768.f);
  float vs = 0.f;
#pragma unroll
  for (int i = 0; i < 3; ++i)
#pragma unroll
    for (int j = 0; j < 4; ++j) { float d = v[i][j] - mu; vs += d * d; }
#pragma unroll
  for (int m = 32; m >= 1; m >>= 1) vs += __shfl_xor(vs, m);
  const float rstd = rsqrtf(vs * (1.f / 768.f) + 1e-5f);
  bf16* r1 = o1 + (size_t)row * CD;
  bf16* r2 = o2 + (size_t)row * CD;
#pragma unroll
  for (int i = 0; i < 3; ++i) {
    const int c4 = lane + 64 * i;
    f32x4 gg1 = ((const f32x4*)g1)[c4], bb1 = ((const f32x4*)b1)[c4];
    f32x4 gg2 = ((const f32x4*)g2)[c4], bb2 = ((const f32x4*)b2)[c4];
    bf16x4 oa, ob;
#pragma unroll
    for (int j = 0; j < 4; ++j) {
      float n = (v[i][j] - mu) * rstd;
      oa[j] = (bf16)(n * gg1[j] + bb1[j]);
      ob[j] = (bf16)(n * gg2[j] + bb2[j]);
    }
    *(bf16x4*)(r1 + c4 * 4) = oa;
    *(bf16x4*)(r2 + c4 * 4) = ob;
  }
}

// ---------------------------------------------------------------------------
// GEMM 256x256, BK=64, 8 waves (2M x 4N), 8-phase schedule (T2+T3+T4+T5).
// Proven-best configuration (fc1 = 88 us measured, R5/R10).
// Optional split-K: kp = wg / bpk (A,Bt offset kp*Klen; output offset
// kp*kpstride elements; bias only kp==0).
// EPI: 0 = f32 store, 1 = bf16 store, 2 = fast-GELU -> bf16 store
// ---------------------------------------------------------------------------
#define GBAR() __builtin_amdgcn_s_barrier()

#define LOADA(MH, BUF)                                                      \
  _Pragma("unroll") for (int m_ = 0; m_ < 4; ++m_) {                        \
    af[m_][0] =                                                             \
        *(const bf16x8*)&As[BUF][((MH)*128 + arow + m_ * 16) * 64 + ach0];  \
    af[m_][1] =                                                             \
        *(const bf16x8*)&As[BUF][((MH)*128 + arow + m_ * 16) * 64 + ach1];  \
  }

#define LOADB(DST, NH, BUF)                                                 \
  _Pragma("unroll") for (int n_ = 0; n_ < 2; ++n_) {                        \
    DST[n_][0] =                                                            \
        *(const bf16x8*)&Bs[BUF][(brow + (NH)*32 + n_ * 16) * 64 + ach0];   \
    DST[n_][1] =                                                            \
        *(const bf16x8*)&Bs[BUF][(brow + (NH)*32 + n_ * 16) * 64 + ach1];   \
  }

#define MFMA_PH(MH, NH, BF)                                                 \
  __builtin_amdgcn_s_setprio(1);                                            \
  _Pragma("unroll") for (int m_ = 0; m_ < 4; ++m_)                          \
  _Pragma("unroll") for (int n_ = 0; n_ < 2; ++n_) {                        \
    acc[(MH)*4 + m_][(NH)*2 + n_] =                                         \
        mfma16(af[m_][0], BF[n_][0], acc[(MH)*4 + m_][(NH)*2 + n_]);        \
    acc[(MH)*4 + m_][(NH)*2 + n_] =                                         \
        mfma16(af[m_][1], BF[n_][1], acc[(MH)*4 + m_][(NH)*2 + n_]);        \
  }                                                                         \
  __builtin_amdgcn_s_setprio(0);

template <int EPI>
__global__ __launch_bounds__(512, 2) void gemm256(
    const bf16* __restrict__ A, const bf16* __restrict__ Bt,
    const float* __restrict__ bias, void* __restrict__ Cout, int N, int Klen,
    int ldk, int nbn, int bpk, size_t kpstride) {
  __shared__ bf16 As[2][16384];
  __shared__ bf16 Bs[2][16384];
  const int t = threadIdx.x, lane = t & 63, w = t >> 6;
  const int wm = w >> 2, wn = w & 3;

  // bijective XCD-chunked remap (gridDim.x % 8 == 0 by construction)
  const int chunkg = gridDim.x >> 3;
  const int wg = (blockIdx.x & 7) * chunkg + (blockIdx.x >> 3);
  const int kp = wg / bpk, rem = wg % bpk;
  const int bm = rem / nbn, bn = rem % nbn;

  f32x4 acc[8][4] = {};

  const int srow = t >> 3;
  const int scol = ((t & 7) ^ (srow & 7)) << 3;
  const size_t koff = (size_t)kp * Klen;
  const bf16* Ab = A + (size_t)(bm * 256 + srow) * ldk + koff + scol;
  const bf16* Bb = Bt + (size_t)(bn * 256 + srow) * ldk + koff + scol;
  const size_t r64 = (size_t)64 * ldk;

  auto stage_a = [&](int buf, int h, int kt) {
    const bf16* g = Ab + (size_t)h * 128 * ldk + (size_t)kt * 64;
    gload16(g, &As[buf][h * 8192 + w * 512]);
    gload16(g + r64, &As[buf][h * 8192 + 4096 + w * 512]);
  };
  auto stage_b = [&](int buf, int h, int kt) {
    const bf16* g = Bb + (size_t)h * 128 * ldk + (size_t)kt * 64;
    gload16(g, &Bs[buf][h * 8192 + w * 512]);
    gload16(g + r64, &Bs[buf][h * 8192 + 4096 + w * 512]);
  };

  const int arow = wm * 64 + (lane & 15);
  const int brow = wn * 64 + (lane & 15);
  const int ach0 = (((lane >> 4) + 0) ^ (lane & 7)) << 3;
  const int ach1 = (((lane >> 4) + 4) ^ (lane & 7)) << 3;

  // prologue: T0 {A0,B0,B1,A1}, T1 {A0,B0}
  stage_a(0, 0, 0); stage_b(0, 0, 0); stage_b(0, 1, 0); stage_a(0, 1, 0);
  stage_a(1, 0, 1); stage_b(1, 0, 1);
  asm volatile("s_waitcnt vmcnt(4)" ::: "memory");  // T0 landed
  GBAR();

  const int NT = Klen >> 6, NI = NT >> 1;
  bf16x8 af[4][2], bf0[2][2], bf1[2][2];

  for (int j = 0; j < NI; ++j) {
    const int tA = 2 * j, tB = 2 * j + 1;
    const bool notlast = (j + 1 < NI);

    // ======== tile tA from buf 0 ========
    LOADA(0, 0);
    LOADB(bf0, 0, 0);
    stage_b(1, 1, tB);
    GBAR();
    MFMA_PH(0, 0, bf0);
    GBAR();
    LOADB(bf1, 1, 0);
    stage_a(1, 1, tB);
    GBAR();
    MFMA_PH(0, 1, bf1);
    GBAR();
    LOADA(1, 0);
    if (notlast) stage_a(0, 0, tA + 2);
    GBAR();
    MFMA_PH(1, 0, bf0);
    GBAR();
    if (notlast) {
      stage_b(0, 0, tA + 2);
      asm volatile("s_waitcnt vmcnt(4)" ::: "memory");
    } else {
      asm volatile("s_waitcnt vmcnt(0)" ::: "memory");
    }
    GBAR();
    MFMA_PH(1, 1, bf1);
    GBAR();

    // ======== tile tB from buf 1 ========
    LOADA(0, 1);
    LOADB(bf0, 0, 1);
    if (notlast) stage_b(0, 1, tA + 2);
    GBAR();
    MFMA_PH(0, 0, bf0);
    GBAR();
    LOADB(bf1, 1, 1);
    if (notlast) stage_a(0, 1, tA + 2);
    GBAR();
    MFMA_PH(0, 1, bf1);
    GBAR();
    LOADA(1, 1);
    if (notlast) stage_a(1, 0, tB + 2);
    GBAR();
    MFMA_PH(1, 0, bf0);
    GBAR();
    if (notlast) {
      stage_b(1, 0, tB + 2);
      asm volatile("s_waitcnt vmcnt(4)" ::: "memory");
    }
    GBAR();
    MFMA_PH(1, 1, bf1);
    GBAR();
  }

  // epilogue (bias only on kp==0 so split-K partials sum correctly)
#pragma unroll
  for (int am = 0; am < 8; ++am) {
    const int grow0 =
        bm * 256 + (am >> 2) * 128 + wm * 64 + (am & 3) * 16 + (lane >> 4) * 4;
#pragma unroll
    for (int an = 0; an < 4; ++an) {
      const int gcol = bn * 256 + wn * 64 + an * 16 + (lane & 15);
      const float bv = (kp == 0) ? bias[gcol] : 0.f;
#pragma unroll
      for (int r = 0; r < 4; ++r) {
        float v = acc[am][an][r] + bv;
        if (EPI == 2) v = fast_gelu(v);
        const size_t idx = (size_t)(grow0 + r) * N + gcol + kp * kpstride;
        if (EPI == 0) ((float*)Cout)[idx] = v;
        else ((bf16*)Cout)[idx] = (bf16)v;
      }
    }
  }
}

// ---------------------------------------------------------------------------
// Flash attention v2 — swapped-operand 32x32 MFMA, in-register softmax.
// launch_bounds(256,4): 4 blocks/CU -> all 960 blocks in one dispatch round.
// ---------------------------------------------------------------------------
__global__ __launch_bounds__(256, 4) void attn_v2(
    const bf16* __restrict__ qkv, bf16* __restrict__ obuf) {
  __shared__ bf16 Ks[2][4096];
  __shared__ bf16 Vt[2][4096];
  const int t = threadIdx.x, lane = t & 63, w = t >> 6;
  const int g = lane >> 5, q32 = lane & 31, rq7 = q32 & 7;

  const int xcd = blockIdx.x & 7, slot = blockIdx.x >> 3;
  const int work = xcd * 120 + slot;
  const int sbh = work >> 3, qt = work & 7;
  const int sb = sbh / NH, h = sbh % NH;
  const size_t tokbase = (size_t)sb * SEQ;
  const int qoff = h * 64, koff = CD + h * 64, voff = 2 * CD + h * 64;

  const int qrow = qt * 128 + w * 32 + q32;
  bf16x8 qf[4];
  {
    const bf16* qp = qkv + (tokbase + qrow) * NQKV + qoff + g * 8;
#pragma unroll
    for (int kd = 0; kd < 4; ++kd) {
      bf16x8 v = *(const bf16x8*)(qp + kd * 16);
#pragma unroll
      for (int j = 0; j < 8; ++j) v[j] = (bf16)((float)v[j] * 0.125f);
      qf[kd] = v;
    }
  }

  const int skv1 = t >> 3, sc1 = (t & 7) ^ (skv1 & 7);
  const int skv2 = (t + 256) >> 3, sc2 = (t & 7) ^ (skv2 & 7);
  const int vkv0 = 2 * (t & 31);
  const int vd0 = 8 * (t >> 5);
  const int c0 = (vkv0 & 51) | ((vkv0 & 4) << 1) | ((vkv0 & 8) >> 1);
  const int vchunk = c0 >> 3, vsub = c0 & 7;
  const bf16* kbase = qkv + tokbase * NQKV + koff;
  const bf16* vbase = qkv + tokbase * NQKV + voff;

  {
    const bf16* kb0 = kbase;
    gload16(kb0 + (size_t)skv1 * NQKV + sc1 * 8, &Ks[0][w * 512]);
    gload16(kb0 + (size_t)skv2 * NQKV + sc2 * 8, &Ks[0][2048 + w * 512]);
    const bf16* vp = vbase + (size_t)vkv0 * NQKV + vd0;
    bf16x8 r0 = *(const bf16x8*)vp;
    bf16x8 r1 = *(const bf16x8*)(vp + NQKV);
#pragma unroll
    for (int j = 0; j < 8; ++j) {
      const int d = vd0 + j;
      *(unsigned*)&Vt[0][d * 64 + ((vchunk ^ j) << 3) + vsub] =
          pack2(r0[j], r1[j]);
    }
  }
  __syncthreads();

  float m_run = -1e30f, l_run = 0.f;
  f32x16 oT0 = {}, oT1 = {};
  int cur = 0;

  for (int kt = 0; kt < 16; ++kt) {
    bf16x8 nv0, nv1;
    if (kt < 15) {
      const bf16* vp = vbase + (size_t)((kt + 1) * 64 + vkv0) * NQKV + vd0;
      nv0 = *(const bf16x8*)vp;
      nv1 = *(const bf16x8*)(vp + NQKV);
      const bf16* kb0 = kbase + (size_t)(kt + 1) * 64 * NQKV;
      gload16(kb0 + (size_t)skv1 * NQKV + sc1 * 8, &Ks[cur ^ 1][w * 512]);
      gload16(kb0 + (size_t)skv2 * NQKV + sc2 * 8,
              &Ks[cur ^ 1][2048 + w * 512]);
    }

    f32x16 sT0 = {}, sT1 = {};
#pragma unroll
    for (int kd = 0; kd < 4; ++kd) {
      bf16x8 kf0 =
          *(const bf16x8*)&Ks[cur][q32 * 64 + (((2 * kd + g) ^ rq7) << 3)];
      bf16x8 kf1 = *(const bf16x8*)&Ks[cur][(32 + q32) * 64 +
                                            (((2 * kd + g) ^ rq7) << 3)];
      sT0 = mfma32(kf0, qf[kd], sT0);
      sT1 = mfma32(kf1, qf[kd], sT1);
    }

    float mt = sT0[0];
#pragma unroll
    for (int r = 1; r < 16; ++r) mt = fmaxf(mt, sT0[r]);
#pragma unroll
    for (int r = 0; r < 16; ++r) mt = fmaxf(mt, sT1[r]);
    mt = fmaxf(mt, __shfl_xor(mt, 32));
    const float mnew = fmaxf(m_run, mt);
    const float alpha = __expf(m_run - mnew);
    m_run = mnew;
    float rs = 0.f;
#pragma unroll
    for (int r = 0; r < 16; ++r) {
      sT0[r] = __expf(sT0[r] - mnew);
      rs += sT0[r];
    }
#pragma unroll
    for (int r = 0; r < 16; ++r) {
      sT1[r] = __expf(sT1[r] - mnew);
      rs += sT1[r];
    }
    rs += __shfl_xor(rs, 32);
    l_run = l_run * alpha + rs;
#pragma unroll
    for (int r = 0; r < 16; ++r) { oT0[r] *= alpha; oT1[r] *= alpha; }

    bf16x8 pa[4];
#pragma unroll
    for (int hh = 0; hh < 2; ++hh)
#pragma unroll
      for (int j = 0; j < 8; ++j) {
        pa[hh][j] = (bf16)sT0[8 * hh + j];
        pa[2 + hh][j] = (bf16)sT1[8 * hh + j];
      }

#pragma unroll
    for (int ks = 0; ks < 4; ++ks) {
      bf16x8 vf0 =
          *(const bf16x8*)&Vt[cur][q32 * 64 + (((2 * ks + g) ^ rq7) << 3)];
      bf16x8 vf1 = *(const bf16x8*)&Vt[cur][(32 + q32) * 64 +
                                            (((2 * ks + g) ^ rq7) << 3)];
      oT0 = mfma32(vf0, pa[ks], oT0);
      oT1 = mfma32(vf1, pa[ks], oT1);
    }

    if (kt < 15) {
#pragma unroll
      for (int j = 0; j < 8; ++j) {
        const int d = vd0 + j;
        *(unsigned*)&Vt[cur ^ 1][d * 64 + ((vchunk ^ j) << 3) + vsub] =
            pack2(nv0[j], nv1[j]);
      }
    }
    __syncthreads();
    cur ^= 1;
  }

  const float rl = 1.f / l_run;
  bf16* orow = obuf + (tokbase + qrow) * CD + h * 64;
#pragma unroll
  for (int m = 0; m < 4; ++m) {
    bf16x4 o0, o1;
#pragma unroll
    for (int r = 0; r < 4; ++r) {
      o0[r] = (bf16)(oT0[4 * m + r] * rl);
      o1[r] = (bf16)(oT1[4 * m + r] * rl);
    }
    *(bf16x4*)(orow + 8 * m + 4 * g) = o0;
    *(bf16x4*)(orow + 32 + 8 * m + 4 * g) = o1;
  }
}

// ---------------------------------------------------------------------------
// Adapter: out = ((X@dw+db)@mw+mb)@uw+ub ; X bf16 [TOK][768], out bf16.
// ---------------------------------------------------------------------------
__global__ __launch_bounds__(256) void adapter_kernel(
    const bf16* __restrict__ X, const float* __restrict__ dw,
    const float* __restrict__ db, const float* __restrict__ mw,
    const float* __restrict__ mb, const float* __restrict__ uw,
    const float* __restrict__ ub, bf16* __restrict__ out) {
  const int tok = blockIdx.x * 4 + (threadIdx.x >> 6);
  const int lane = threadIdx.x & 63;
  const bf16* xr = X + (size_t)tok * CD;
  float xv[12];
#pragma unroll
  for (int i = 0; i < 12; ++i) xv[i] = (float)xr[lane + 64 * i];
  float h1[8] = {0, 0, 0, 0, 0, 0, 0, 0};
#pragma unroll
  for (int i = 0; i < 12; ++i) {
    const f32x4* dr = (const f32x4*)(dw + (size_t)(lane + 64 * i) * 8);
    f32x4 d0 = dr[0], d1 = dr[1];
#pragma unroll
    for (int j = 0; j < 4; ++j) {
      h1[j] += xv[i] * d0[j];
      h1[4 + j] += xv[i] * d1[j];
    }
  }
#pragma unroll
  for (int m = 1; m < 64; m <<= 1)
#pragma unroll
    for (int j = 0; j < 8; ++j) h1[j] += __shfl_xor(h1[j], m);
#pragma unroll
  for (int j = 0; j < 8; ++j) h1[j] += db[j];
  float h2[8];
#pragma unroll
  for (int k = 0; k < 8; ++k) {
    float v = mb[k];
#pragma unroll
    for (int j = 0; j < 8; ++j) v += h1[j] * mw[j * 8 + k];
    h2[k] = v;
  }
#pragma unroll
  for (int i = 0; i < 12; ++i) {
    const int c = lane + 64 * i;
    float v = ub[c];
#pragma unroll
    for (int k = 0; k < 8; ++k) v += h2[k] * uw[k * CD + c];
    out[(size_t)tok * CD + c] = (bf16)v;
  }
}

// ---------------------------------------------------------------------------
// Final: z[s] = ys[s](bf16) + m0[s] + m1[s] + cross(a2)   (out f32)
// ---------------------------------------------------------------------------
__global__ __launch_bounds__(256) void cross_residual(
    const bf16* __restrict__ ys, const bf16* __restrict__ m01,
    const bf16* __restrict__ a, float* __restrict__ out) {
  const int s = blockIdx.y;
  const size_t i = (size_t)blockIdx.x * 256 + threadIdx.x;  // group-of-4 index
  const size_t spitch = (size_t)2048 * 768 / 4;
  const size_t sb = (size_t)s * spitch;
  const size_t mstride = (size_t)TOK * CD / 4;
  f32x4 v = b4tof(ys + (sb + i) * 4);
  v += b4tof(m01 + (sb + i) * 4);
  v += b4tof(m01 + (mstride + sb + i) * 4);
  if (s > 0) v += b4tof(a + (sb - spitch + i) * 4);
  if (s < 4) v += b4tof(a + (sb + spitch + i) * 4);
  ((f32x4*)out)[sb + i] = v;
}

// ---------------------------------------------------------------------------
// workspace layout (bytes; ~203 MB)
// ---------------------------------------------------------------------------
#define OFF_WTQKV  ((size_t)0)           // bf16 [2304][768]
#define OFF_WTPROJ ((size_t)3538944)     // bf16 [768][768]
#define OFF_WTFC1  ((size_t)4718592)     // bf16 [3072][768]
#define OFF_WTFC2  ((size_t)9437184)     // bf16 [768][3072]
#define OFF_N1     ((size_t)14155776)    // bf16 [10240][768]; later ln1(ys)
#define OFF_BIG    ((size_t)29884416)    // bf16 qkv [10240][2304]; later h
#define OFF_OBUF   ((size_t)77070336)    // bf16 o [10240][768]
#define OFF_AOM    ((size_t)92798976)    // bf16 partial pairs (proj, then fc2)
#define OFF_A12    ((size_t)124256256)   // bf16 [10240][768]: a1, later a2
#define OFF_YS     ((size_t)155713536)   // bf16 [10240][768] ys
#define OFF_L2Y    ((size_t)187170816)   // bf16 [10240][768]

extern "C" void kernel_launch(void* const* d_in, const int* in_sizes, int n_in,
                              void* d_out, int out_size, void* d_ws,
                              size_t ws_size, hipStream_t stream) {
  const float* x0 = (const float*)d_in[0];
  const float* x1 = (const float*)d_in[1];
  const float* x2 = (const float*)d_in[2];
  const float* x3 = (const float*)d_in[3];
  const float* x4 = (const float*)d_in[4];
  const float* ln1_g = (const float*)d_in[5];
  const float* ln1_b = (const float*)d_in[6];
  const float* ln2_g = (const float*)d_in[7];
  const float* ln2_b = (const float*)d_in[8];
  const float* qkv_w = (const float*)d_in[9];
  const float* qkv_b = (const float*)d_in[10];
  const float* proj_w = (const float*)d_in[11];
  const float* proj_b = (const float*)d_in[12];
  const float* fc1_w = (const float*)d_in[13];
  const float* fc1_b = (const float*)d_in[14];
  const float* fc2_w = (const float*)d_in[15];
  const float* fc2_b = (const float*)d_in[16];
  const float* at_dw = (const float*)d_in[17];
  const float* at_db = (const float*)d_in[18];
  const float* at_mw = (const float*)d_in[19];
  const float* at_mb = (const float*)d_in[20];
  const float* at_uw = (const float*)d_in[21];
  const float* at_ub = (const float*)d_in[22];
  const float* a2_dw = (const float*)d_in[23];
  const float* a2_db = (const float*)d_in[24];
  const float* a2_mw = (const float*)d_in[25];
  const float* a2_mb = (const float*)d_in[26];
  const float* a2_uw = (const float*)d_in[27];
  const float* a2_ub = (const float*)d_in[28];

  char* ws = (char*)d_ws;
  bf16* wt_qkv = (bf16*)(ws + OFF_WTQKV);
  bf16* wt_proj = (bf16*)(ws + OFF_WTPROJ);
  bf16* wt_fc1 = (bf16*)(ws + OFF_WTFC1);
  bf16* wt_fc2 = (bf16*)(ws + OFF_WTFC2);
  bf16* n1 = (bf16*)(ws + OFF_N1);
  bf16* qkvb = (bf16*)(ws + OFF_BIG);
  bf16* obuf = (bf16*)(ws + OFF_OBUF);
  bf16* mbuf = (bf16*)(ws + OFF_AOM);  // split-K bf16 partial pair
  bf16* a12 = (bf16*)(ws + OFF_A12);
  bf16* ysb = (bf16*)(ws + OFF_YS);
  bf16* l2y = (bf16*)(ws + OFF_L2Y);

  const dim3 b256(256);
  const dim3 b512(512);

  // 1. all weight convert+transposes in one launch (6912 tiles)
  transpose_all<<<6912, b256, 0, stream>>>(qkv_w, proj_w, fc1_w, fc2_w,
                                           wt_qkv, wt_proj, wt_fc1, wt_fc2);

  // 2. n1 = LN(xs)  (bf16)
  ln5_kernel<<<2560, b256, 0, stream>>>(x0, x1, x2, x3, x4, ln1_g, ln1_b, n1);

  // 3. qkv = n1 @ qkv_w + qkv_b  (bf16)   grid 40*9=360
  gemm256<1><<<360, b512, 0, stream>>>(n1, wt_qkv, qkv_b, qkvb, NQKV, 768, 768,
                                       9, 360, 0);

  // 4. a1 = adapter(n1)  (bf16)
  adapter_kernel<<<2560, b256, 0, stream>>>(n1, at_dw, at_db, at_mw, at_mb,
                                            at_uw, at_ub, a12);

  // 5. attention -> o (bf16)
  attn_v2<<<960, b256, 0, stream>>>(qkvb, obuf);

  // 6. ao = o @ proj_w + proj_b  — split-K=2, bf16 partials (grid 240)
  gemm256<1><<<240, b512, 0, stream>>>(obuf, wt_proj, proj_b, mbuf, CD, 384,
                                       768, 3, 120, (size_t)TOK * CD);

  // 7+8. ys = xs + (ao0+ao1) + cross(a1) (bf16); ln1(ys)->n1, ln2(ys)->l2y
  fuse_res_ln<<<2560, b256, 0, stream>>>(x0, x1, x2, x3, x4, mbuf, a12, ysb,
                                         ln1_g, ln1_b, ln2_g, ln2_b, n1, l2y);

  // 9. a2 = adapter(ln1(ys))  (bf16, overwrites a1)
  adapter_kernel<<<2560, b256, 0, stream>>>(n1, a2_dw, a2_db, a2_mw, a2_mb,
                                            a2_uw, a2_ub, a12);

  // 10. h = gelu(ln2(ys) @ fc1_w + fc1_b)  (bf16)   grid 40*12=480
  gemm256<2><<<480, b512, 0, stream>>>(l2y, wt_fc1, fc1_b, qkvb, NHID, 768,
                                       768, 12, 480, 0);

  // 11. m = h @ fc2_w + fc2_b  — split-K=2, bf16 partials m0,m1
  gemm256<1><<<240, b512, 0, stream>>>(qkvb, wt_fc2, fc2_b, mbuf, CD, 1536,
                                       3072, 3, 120, (size_t)TOK * CD);

  // 12. z = ys + (m0+m1) + cross(a2) -> d_out
  cross_residual<<<dim3(1536, 5), b256, 0, stream>>>(ysb, mbuf, a12,
                                                     (float*)d_out);
}